// Round 6
// baseline (1258.142 us; speedup 1.0000x reference)
//
#include <hip/hip_runtime.h>

typedef short  bhalf8  __attribute__((ext_vector_type(8)));
typedef float  floatx4 __attribute__((ext_vector_type(4)));
typedef unsigned long long u64;

namespace {
constexpr int kDim   = 256;
constexpr int kCodes = 8192;
constexpr int kRows  = 16384;   // 16 * 32 * 32
constexpr int kOutZq   = 16 * 256 * 32 * 32;  // 4194304
constexpr int kOutLoss = kOutZq;
constexpr int kOutIdx  = kOutZq + 1;
constexpr int kNT = kCodes / 128;             // 64 N-tiles
constexpr unsigned kCap = 262144;
constexpr float kMargin = 4e-5f;  // half-bin 1.53e-5 + ~16 sigma approx err

// ---- fast ws layout (bytes): single-pass GEMM + tt top-2 table ----
constexpr size_t kOffZf    = 0;                                   // 8 MB
constexpr size_t kOffCbf   = kOffZf   + (size_t)kRows  * kDim * 2; // 4 MB
constexpr size_t kOffSrow  = kOffCbf  + (size_t)kCodes * kDim * 2;
constexpr size_t kOffTt    = kOffSrow + (size_t)kRows * 4;        // 16 MB
constexpr size_t kOffPack  = kOffTt   + (size_t)kNT * kRows * 16;
constexpr size_t kOffList  = kOffPack + (size_t)kRows * 8;
constexpr size_t kOffCnt   = kOffList + (size_t)kCap * 8;
constexpr size_t kOffBloss = kOffCnt  + 256;
constexpr size_t kWsFast   = kOffBloss + (size_t)(kRows / 4) * 8; // ~30.2 MB

// ---- mid ws layout (exact R5, proven available: 18.3 MB) ----
constexpr size_t kM_Srow  = kOffCbf  + (size_t)kCodes * kDim * 2;
constexpr size_t kM_Rmax  = kM_Srow  + (size_t)kRows * 4;
constexpr size_t kM_RmaxP = kM_Rmax  + (size_t)kRows * 4;         // 4 MB
constexpr size_t kM_Pack  = kM_RmaxP + (size_t)kNT * kRows * 4;
constexpr size_t kM_List  = kM_Pack  + (size_t)kRows * 8;
constexpr size_t kM_Cnt   = kM_List  + (size_t)kCap * 8;
constexpr size_t kM_Bloss = kM_Cnt   + 256;
constexpr size_t kWsMid   = kM_Bloss + (size_t)(kRows / 4) * 8;
}

__device__ inline unsigned short f2bf(float f) {  // RNE f32 -> bf16
  unsigned u = __float_as_uint(f);
  u += 0x7fffu + ((u >> 16) & 1u);
  return (unsigned short)(u >> 16);
}

__device__ inline void gload_lds16(const void* g, void* l) {
  __builtin_amdgcn_global_load_lds(
      (const __attribute__((address_space(1))) unsigned int*)(g),
      (__attribute__((address_space(3))) unsigned int*)(l), 16, 0, 0);
}

// XCD super-tile map: bid%8 = XCD (perf-only assumption). Each XCD owns a
// fixed set of 8 m-tiles (1 MB zF, L2-persistent) and sweeps nt in 8 passes
// of 8 nt-tiles (512 KB cbF per pass) -> cross-L2 traffic ~50 MB total.
__device__ inline void tile_map(int bid, int& mt, int& nt) {
  const int xcd = bid & 7, slot = bid >> 3;
  mt = xcd * 8 + (slot & 7);
  nt = (slot >> 6) * 8 + ((slot >> 3) & 7);
}

__device__ inline bool lexgt(float v, int iv, float w, int iw) {
  return v > w || (v == w && iv < iw);
}

// z [b][d][hw] f32 -> zF fragment order [kb=8][rt=1024][lane=64][8] bf16.
__global__ __launch_bounds__(256) void vq_convz(const float* __restrict__ z,
                                                unsigned short* __restrict__ zF) {
  const int t    = blockIdx.x * 256 + threadIdx.x;
  const int kb   = t >> 16;
  const int rt   = (t >> 6) & 1023;
  const int lane = t & 63;
  const int m  = rt * 16 + (lane & 15);
  const int k0 = kb * 32 + (lane >> 4) * 8;
  const int b  = m >> 10, hw = m & 1023;
  const float* zp = z + ((size_t)b << 18) + hw;
  bhalf8 v;
#pragma unroll
  for (int j = 0; j < 8; ++j)
    v[j] = (short)f2bf(zp[(size_t)(k0 + j) << 10]);
  *reinterpret_cast<bhalf8*>(&zF[(size_t)t << 3]) = v;
}

// cb [n][d] f32 -> cbF fragment order [kb=8][ct=512][lane=64][8] bf16.
__global__ __launch_bounds__(256) void vq_convcb(const float* __restrict__ cb,
                                                 unsigned short* __restrict__ cbF) {
  const int t    = blockIdx.x * 256 + threadIdx.x;
  const int kb   = t >> 15;
  const int ct   = (t >> 6) & 511;
  const int lane = t & 63;
  const int col = ct * 16 + (lane & 15);
  const int k0  = kb * 32 + (lane >> 4) * 8;
  const float4 a = *reinterpret_cast<const float4*>(&cb[(size_t)col * kDim + k0]);
  const float4 c = *reinterpret_cast<const float4*>(&cb[(size_t)col * kDim + k0 + 4]);
  bhalf8 v;
  v[0] = (short)f2bf(a.x); v[1] = (short)f2bf(a.y);
  v[2] = (short)f2bf(a.z); v[3] = (short)f2bf(a.w);
  v[4] = (short)f2bf(c.x); v[5] = (short)f2bf(c.y);
  v[6] = (short)f2bf(c.z); v[7] = (short)f2bf(c.w);
  *reinterpret_cast<bhalf8*>(&cbF[(size_t)t << 3]) = v;
}

// Per-row s = sum(z^2), EXACT same f32 op order as the validated R2 kernel.
__global__ __launch_bounds__(256) void vq_rows(const float* __restrict__ z,
                                               float* __restrict__ srow,
                                               u64* __restrict__ pack,
                                               unsigned* __restrict__ cnt) {
  const int m  = blockIdx.x * 256 + threadIdx.x;
  const int b  = m >> 10, hw = m & 1023;
  const float* zp = z + ((size_t)b << 18) + hw;
  float r8[8];
#pragma unroll
  for (int j = 0; j < 8; ++j) {
    const float v = zp[(size_t)j << 10];
    r8[j] = __fmul_rn(v, v);
  }
  for (int d = 8; d < kDim; d += 8) {
#pragma unroll
    for (int j = 0; j < 8; ++j) {
      const float v = zp[(size_t)(d + j) << 10];
      r8[j] = __fadd_rn(r8[j], __fmul_rn(v, v));
    }
  }
  srow[m] = __fadd_rn(
      __fadd_rn(__fadd_rn(r8[0], r8[1]), __fadd_rn(r8[2], r8[3])),
      __fadd_rn(__fadd_rn(r8[4], r8[5]), __fadd_rn(r8[6], r8[7])));
  pack[m] = ~0ull;
  if (m == 0) *cnt = 0u;
}

// Single-pass bf16 MFMA GEMM (256 rows x 128 cols/block, 4 waves x 64 rows).
// A direct from zF (global), B double-buffered LDS via global_load_lds.
// Output: per-(row, nt) approx top-2 (score,idx) pairs to tt.
__global__ __launch_bounds__(256, 2) void vq_gemm1(
    const unsigned short* __restrict__ zF,
    const unsigned short* __restrict__ cbF,
    float4* __restrict__ tt) {
  __shared__ __align__(16) unsigned short Bs[2][4096];  // 8 KB each
  const int tid  = threadIdx.x;
  int mt, nt;
  tile_map(blockIdx.x, mt, nt);
  const int m0   = mt * 256, n0 = nt * 128;
  const int w    = tid >> 6, lane = tid & 63;
  const int r16  = lane & 15, kg = lane >> 4;

  floatx4 acc[4][8];
#pragma unroll
  for (int i = 0; i < 4; ++i)
#pragma unroll
    for (int j = 0; j < 8; ++j) acc[i][j] = floatx4{0.f, 0.f, 0.f, 0.f};

  auto stage = [&](int kb, int buf) {
    const unsigned short* src = cbF + (((size_t)(kb * 512 + nt * 8)) << 9);
#pragma unroll
    for (int i = 0; i < 2; ++i)
      gload_lds16(src + (((i * 256 + tid)) << 3),
                  &Bs[buf][(i * 256 + w * 64) << 3]);
  };
  const int rtw = mt * 16 + w * 4;
  auto loadA = [&](int kb, bhalf8* af) {
#pragma unroll
    for (int mi = 0; mi < 4; ++mi)
      af[mi] = *reinterpret_cast<const bhalf8*>(
          &zF[((size_t)((kb * 1024 + rtw + mi) * 64 + lane)) << 3]);
  };

  bhalf8 afc[4], afn[4];
  stage(0, 0);
  loadA(0, afc);
  __syncthreads();

#pragma unroll
  for (int kb = 0; kb < 8; ++kb) {
    const int cur = kb & 1;
    if (kb < 7) {
      stage(kb + 1, cur ^ 1);
      loadA(kb + 1, afn);
    }
    bhalf8 bf[8];
#pragma unroll
    for (int ni = 0; ni < 8; ++ni)
      bf[ni] = *reinterpret_cast<const bhalf8*>(&Bs[cur][(ni * 64 + lane) << 3]);
#pragma unroll
    for (int mi = 0; mi < 4; ++mi)
#pragma unroll
      for (int ni = 0; ni < 8; ++ni)
        acc[mi][ni] = __builtin_amdgcn_mfma_f32_16x16x32_bf16(
            afc[mi], bf[ni], acc[mi][ni], 0, 0, 0);
    __syncthreads();
#pragma unroll
    for (int mi = 0; mi < 4; ++mi) afc[mi] = afn[mi];
  }

  // Per-row top-2 across the 128-code tile.
  // C frag mapping: col = lane&15, row = (lane>>4)*4 + reg.
#pragma unroll
  for (int mi = 0; mi < 4; ++mi)
#pragma unroll
    for (int reg = 0; reg < 4; ++reg) {
      float a1 = acc[mi][0][reg];
      int   i1 = n0 + r16;
      float a2 = -3.4e38f;
      int   i2 = 0x7fffffff;
#pragma unroll
      for (int ni = 1; ni < 8; ++ni) {
        const float v = acc[mi][ni][reg];
        const int  ix = n0 + ni * 16 + r16;
        if (lexgt(v, ix, a1, i1)) { a2 = a1; i2 = i1; a1 = v; i1 = ix; }
        else if (lexgt(v, ix, a2, i2)) { a2 = v; i2 = ix; }
      }
#pragma unroll
      for (int off = 1; off < 16; off <<= 1) {
        const float b1 = __shfl_xor(a1, off);
        const int   j1 = __shfl_xor(i1, off);
        const float b2 = __shfl_xor(a2, off);
        const int   j2 = __shfl_xor(i2, off);
        if (lexgt(b1, j1, a1, i1)) {
          if (lexgt(b2, j2, a1, i1)) { a2 = b2; i2 = j2; }
          else                       { a2 = a1; i2 = i1; }
          a1 = b1; i1 = j1;
        } else if (lexgt(b1, j1, a2, i2)) {
          a2 = b1; i2 = j1;
        }
      }
      if (r16 == 0) {
        const int row = m0 + w * 64 + mi * 16 + kg * 4 + reg;
        tt[(size_t)nt * kRows + row] =
            make_float4(a1, __int_as_float(i1), a2, __int_as_float(i2));
      }
    }
}

// Merge: global row-max over tile top-1s; emit within-margin candidates.
// If a tile's SECOND-best is also within margin, flag the whole tile for
// exact rescan (kills the >2-in-one-tile capture hazard entirely).
__global__ __launch_bounds__(256) void vq_mrg(const float4* __restrict__ tt,
                                              u64* __restrict__ list,
                                              unsigned* __restrict__ cnt) {
  const int m = blockIdx.x * 256 + threadIdx.x;
  float M = -3.4e38f;
  for (int nt = 0; nt < kNT; ++nt)
    M = fmaxf(M, tt[(size_t)nt * kRows + m].x);
  const float t = M - kMargin;
  for (int nt = 0; nt < kNT; ++nt) {
    const float4 e = tt[(size_t)nt * kRows + m];
    if (e.z > t) {  // suspicious tile: exact-rescan all 128 codes
      const unsigned slot = atomicAdd(cnt, 1u);
      if (slot < kCap)
        list[slot] = ((u64)(unsigned)m << 32) | 0x80000000u | (unsigned)nt;
    } else if (e.x > t) {
      const unsigned slot = atomicAdd(cnt, 1u);
      if (slot < kCap)
        list[slot] = ((u64)(unsigned)m << 32) | (unsigned)__float_as_int(e.y);
    }
  }
}

// Exact f32 rescore (bit-identical to R2 numerics): sequential ascending-k
// fmaf chain, dv = fl32(s - 2*dot); lex-min (dv, idx) via u64 atomicMin.
__device__ inline void rescore_one(const float* __restrict__ z,
                                   const float* __restrict__ cb,
                                   const float* __restrict__ srow,
                                   u64* __restrict__ pack, int m, int code) {
  const int b = m >> 10, hw = m & 1023;
  const float* zr = z + ((size_t)b << 18) + hw;
  const float* er = cb + (size_t)code * kDim;
  float d = 0.f;
  for (int k = 0; k < kDim; ++k)
    d = fmaf(zr[(size_t)k << 10], er[k], d);
  const float dv = __fsub_rn(srow[m], 2.0f * d);
  atomicMin(pack + m, ((u64)__float_as_uint(dv) << 32) | (unsigned)code);
}

__global__ __launch_bounds__(256) void vq_rescore(
    const float* __restrict__ z, const float* __restrict__ cb,
    const float* __restrict__ srow, const u64* __restrict__ list,
    const unsigned* __restrict__ cnt, u64* __restrict__ pack) {
  const unsigned total = min(*cnt, kCap);
  for (unsigned i = blockIdx.x * 256 + threadIdx.x; i < total;
       i += gridDim.x * 256) {
    const u64 e = list[i];
    const int m   = (int)(e >> 32);
    const unsigned low = (unsigned)(e & 0xffffffffu);
    if (low & 0x80000000u) {
      const int c0 = (int)(low & 63) * 128;
      for (int c = c0; c < c0 + 128; ++c) rescore_one(z, cb, srow, pack, m, c);
    } else {
      rescore_one(z, cb, srow, pack, m, (int)low);
    }
  }
}

// Gather z_q to [B,C,H,W], idx output, f64 loss partials.
__global__ __launch_bounds__(256) void vq_out2(
    const float* __restrict__ z, const float* __restrict__ cb,
    const u64* __restrict__ pack, float* __restrict__ out,
    double* __restrict__ bloss) {
  __shared__ double wsum[4];
  const int tid  = threadIdx.x;
  const int lane = tid & 63;
  const int wv   = tid >> 6;
  const int m    = blockIdx.x * 4 + wv;
  const int b    = m >> 10;
  const int hw   = m & 1023;
  const u64 p = pack[m];
  const int best = (p == ~0ull) ? 0 : (int)(p & 0x7fffffffu);
  const float* zr = z + ((size_t)b << 18) + hw;
  const float* e  = cb + (size_t)best * kDim;
  float* o0 = out + ((size_t)b << 18) + hw;
  double acc = 0;
#pragma unroll
  for (int j = 0; j < 4; ++j) {
    const int d = lane + j * 64;
    const float ev = e[d];
    const float zv = zr[(size_t)d << 10];
    o0[(size_t)d << 10] = ev;
    const double diff = (double)ev - (double)zv;
    acc += diff * diff;
  }
#pragma unroll
  for (int off = 32; off > 0; off >>= 1) acc += __shfl_xor(acc, off);
  if (lane == 0) {
    out[kOutIdx + m] = (float)best;
    wsum[wv] = acc;
  }
  __syncthreads();
  if (tid == 0) bloss[blockIdx.x] = wsum[0] + wsum[1] + wsum[2] + wsum[3];
}

__global__ __launch_bounds__(256) void vq_final(
    const double* __restrict__ bloss, float* __restrict__ out) {
  __shared__ double sm[256];
  double s = 0;
  for (int i = threadIdx.x; i < kRows / 4; i += 256) s += bloss[i];
  sm[threadIdx.x] = s;
  __syncthreads();
  for (int st = 128; st > 0; st >>= 1) {
    if (threadIdx.x < st) sm[threadIdx.x] += sm[threadIdx.x + st];
    __syncthreads();
  }
  if (threadIdx.x == 0)
    out[kOutLoss] = (float)(1.25 * sm[0] / (double)kOutZq);
}

// ---------------- mid fallback: R5 two-phase (proven), + supertile map ----

template <int PHASE>
__global__ __launch_bounds__(256, 2) void vq_gemm2(
    const unsigned short* __restrict__ zF,
    const unsigned short* __restrict__ cbF,
    const float* __restrict__ rowmax, float* __restrict__ rowmaxp,
    u64* __restrict__ list, unsigned* __restrict__ cnt) {
  __shared__ __align__(16) unsigned short Bs[2][4096];
  const int tid  = threadIdx.x;
  int mt, nt;
  tile_map(blockIdx.x, mt, nt);
  const int m0   = mt * 256, n0 = nt * 128;
  const int w    = tid >> 6, lane = tid & 63;
  const int r16  = lane & 15, kg = lane >> 4;

  floatx4 acc[4][8];
#pragma unroll
  for (int i = 0; i < 4; ++i)
#pragma unroll
    for (int j = 0; j < 8; ++j) acc[i][j] = floatx4{0.f, 0.f, 0.f, 0.f};

  auto stage = [&](int kb, int buf) {
    const unsigned short* src = cbF + (((size_t)(kb * 512 + nt * 8)) << 9);
#pragma unroll
    for (int i = 0; i < 2; ++i)
      gload_lds16(src + (((i * 256 + tid)) << 3),
                  &Bs[buf][(i * 256 + w * 64) << 3]);
  };
  const int rtw = mt * 16 + w * 4;
  auto loadA = [&](int kb, bhalf8* af) {
#pragma unroll
    for (int mi = 0; mi < 4; ++mi)
      af[mi] = *reinterpret_cast<const bhalf8*>(
          &zF[((size_t)((kb * 1024 + rtw + mi) * 64 + lane)) << 3]);
  };

  bhalf8 afc[4], afn[4];
  stage(0, 0);
  loadA(0, afc);
  __syncthreads();

#pragma unroll
  for (int kb = 0; kb < 8; ++kb) {
    const int cur = kb & 1;
    if (kb < 7) {
      stage(kb + 1, cur ^ 1);
      loadA(kb + 1, afn);
    }
    bhalf8 bf[8];
#pragma unroll
    for (int ni = 0; ni < 8; ++ni)
      bf[ni] = *reinterpret_cast<const bhalf8*>(&Bs[cur][(ni * 64 + lane) << 3]);
#pragma unroll
    for (int mi = 0; mi < 4; ++mi)
#pragma unroll
      for (int ni = 0; ni < 8; ++ni)
        acc[mi][ni] = __builtin_amdgcn_mfma_f32_16x16x32_bf16(
            afc[mi], bf[ni], acc[mi][ni], 0, 0, 0);
    __syncthreads();
#pragma unroll
    for (int mi = 0; mi < 4; ++mi) afc[mi] = afn[mi];
  }

  if (PHASE == 0) {
#pragma unroll
    for (int mi = 0; mi < 4; ++mi)
#pragma unroll
      for (int reg = 0; reg < 4; ++reg) {
        float v = acc[mi][0][reg];
#pragma unroll
        for (int ni = 1; ni < 8; ++ni) v = fmaxf(v, acc[mi][ni][reg]);
#pragma unroll
        for (int off = 1; off < 16; off <<= 1) v = fmaxf(v, __shfl_xor(v, off));
        if (r16 == 0)
          rowmaxp[(size_t)nt * kRows + m0 + w * 64 + mi * 16 + kg * 4 + reg] = v;
      }
  } else {
#pragma unroll
    for (int mi = 0; mi < 4; ++mi)
#pragma unroll
      for (int reg = 0; reg < 4; ++reg) {
        const int row = m0 + w * 64 + mi * 16 + kg * 4 + reg;
        const float t = rowmax[row] - kMargin;
#pragma unroll
        for (int ni = 0; ni < 8; ++ni) {
          if (acc[mi][ni][reg] > t) {
            const unsigned slot = atomicAdd(cnt, 1u);
            if (slot < kCap)
              list[slot] = ((u64)(unsigned)row << 32) |
                           (unsigned)(n0 + ni * 16 + r16);
          }
        }
      }
  }
}

__global__ __launch_bounds__(256) void vq_rmax(const float* __restrict__ rowmaxp,
                                               float* __restrict__ rowmax) {
  const int m = blockIdx.x * 256 + threadIdx.x;
  float v = rowmaxp[m];
  for (int s = 1; s < kNT; ++s) v = fmaxf(v, rowmaxp[(size_t)s * kRows + m]);
  rowmax[m] = v;
}

extern "C" void kernel_launch(void* const* d_in, const int* in_sizes, int n_in,
                              void* d_out, int out_size, void* d_ws, size_t ws_size,
                              hipStream_t stream) {
  const float* z  = (const float*)d_in[0];
  const float* cb = (const float*)d_in[1];
  float* out = (float*)d_out;

  unsigned short* zF  = (unsigned short*)((char*)d_ws + kOffZf);
  unsigned short* cbF = (unsigned short*)((char*)d_ws + kOffCbf);

  if (ws_size >= kWsFast) {
    float*    srow  = (float*)((char*)d_ws + kOffSrow);
    float4*   tt    = (float4*)((char*)d_ws + kOffTt);
    u64*      pack  = (u64*)((char*)d_ws + kOffPack);
    u64*      list  = (u64*)((char*)d_ws + kOffList);
    unsigned* cnt   = (unsigned*)((char*)d_ws + kOffCnt);
    double*   bloss = (double*)((char*)d_ws + kOffBloss);

    vq_convz  <<<2048, 256, 0, stream>>>(z, zF);
    vq_convcb <<<1024, 256, 0, stream>>>(cb, cbF);
    vq_rows   <<<kRows / 256, 256, 0, stream>>>(z, srow, pack, cnt);
    vq_gemm1  <<<4096, 256, 0, stream>>>(zF, cbF, tt);
    vq_mrg    <<<kRows / 256, 256, 0, stream>>>(tt, list, cnt);
    vq_rescore<<<256, 256, 0, stream>>>(z, cb, srow, list, cnt, pack);
    vq_out2   <<<kRows / 4, 256, 0, stream>>>(z, cb, pack, out, bloss);
    vq_final  <<<1, 256, 0, stream>>>(bloss, out);
  } else {
    float*    srow    = (float*)((char*)d_ws + kM_Srow);
    float*    rowmax  = (float*)((char*)d_ws + kM_Rmax);
    float*    rowmaxp = (float*)((char*)d_ws + kM_RmaxP);
    u64*      pack    = (u64*)((char*)d_ws + kM_Pack);
    u64*      list    = (u64*)((char*)d_ws + kM_List);
    unsigned* cnt     = (unsigned*)((char*)d_ws + kM_Cnt);
    double*   bloss   = (double*)((char*)d_ws + kM_Bloss);

    vq_convz  <<<2048, 256, 0, stream>>>(z, zF);
    vq_convcb <<<1024, 256, 0, stream>>>(cb, cbF);
    vq_rows   <<<kRows / 256, 256, 0, stream>>>(z, srow, pack, cnt);
    vq_gemm2<0><<<4096, 256, 0, stream>>>(zF, cbF, rowmax, rowmaxp, list, cnt);
    vq_rmax   <<<kRows / 256, 256, 0, stream>>>(rowmaxp, rowmax);
    vq_gemm2<1><<<4096, 256, 0, stream>>>(zF, cbF, rowmax, rowmaxp, list, cnt);
    vq_rescore<<<256, 256, 0, stream>>>(z, cb, srow, list, cnt, pack);
    vq_out2   <<<kRows / 4, 256, 0, stream>>>(z, cb, pack, out, bloss);
    vq_final  <<<1, 256, 0, stream>>>(bloss, out);
  }
}

// Round 7
// 573.802 us; speedup vs baseline: 2.1926x; 2.1926x over previous
//
#include <hip/hip_runtime.h>

typedef short  bhalf8  __attribute__((ext_vector_type(8)));
typedef float  floatx4 __attribute__((ext_vector_type(4)));
typedef unsigned long long u64;

namespace {
constexpr int kDim   = 256;
constexpr int kCodes = 8192;
constexpr int kRows  = 16384;   // 16 * 32 * 32
constexpr int kOutZq   = 16 * 256 * 32 * 32;  // 4194304
constexpr int kOutLoss = kOutZq;
constexpr int kOutIdx  = kOutZq + 1;
constexpr int kNT = kCodes / 128;             // 64 N-tiles
constexpr unsigned kCap = 262144;
constexpr float kMargin = 4e-5f;  // half-bin 1.53e-5 + ~16 sigma approx err

// ---- fast ws layout (bytes): single-pass GEMM + tt top-2 table ----
constexpr size_t kOffZf    = 0;                                    // 8 MB
constexpr size_t kOffCbf   = kOffZf   + (size_t)kRows  * kDim * 2; // 4 MB
constexpr size_t kOffSrow  = kOffCbf  + (size_t)kCodes * kDim * 2;
constexpr size_t kOffTt    = kOffSrow + (size_t)kRows * 4;         // 16 MB
constexpr size_t kOffPack  = kOffTt   + (size_t)kNT * kRows * 16;
constexpr size_t kOffList  = kOffPack + (size_t)kRows * 8;
constexpr size_t kOffCnt   = kOffList + (size_t)kCap * 8;
constexpr size_t kOffBloss = kOffCnt  + 256;
constexpr size_t kWsFast   = kOffBloss + (size_t)(kRows / 4) * 8;  // ~30.2 MB

// ---- mid ws layout (exact R5, proven) ----
constexpr size_t kM_Srow  = kOffCbf  + (size_t)kCodes * kDim * 2;
constexpr size_t kM_Rmax  = kM_Srow  + (size_t)kRows * 4;
constexpr size_t kM_RmaxP = kM_Rmax  + (size_t)kRows * 4;
constexpr size_t kM_Pack  = kM_RmaxP + (size_t)kNT * kRows * 4;
constexpr size_t kM_List  = kM_Pack  + (size_t)kRows * 8;
constexpr size_t kM_Cnt   = kM_List  + (size_t)kCap * 8;
constexpr size_t kM_Bloss = kM_Cnt   + 256;
constexpr size_t kWsMid   = kM_Bloss + (size_t)(kRows / 4) * 8;
}

__device__ inline unsigned short f2bf(float f) {  // RNE f32 -> bf16
  unsigned u = __float_as_uint(f);
  u += 0x7fffu + ((u >> 16) & 1u);
  return (unsigned short)(u >> 16);
}

__device__ inline void gload_lds16(const void* g, void* l) {
  __builtin_amdgcn_global_load_lds(
      (const __attribute__((address_space(1))) unsigned int*)(g),
      (__attribute__((address_space(3))) unsigned int*)(l), 16, 0, 0);
}

// XCD super-tile map (perf-only): bid%8 = XCD; each XCD owns 8 m-tiles.
__device__ inline void tile_map(int bid, int& mt, int& nt) {
  const int xcd = bid & 7, slot = bid >> 3;
  mt = xcd * 8 + (slot & 7);
  nt = (slot >> 6) * 8 + ((slot >> 3) & 7);
}

__device__ inline bool lexgt(float v, int iv, float w, int iw) {
  return v > w || (v == w && iv < iw);
}

// z [b][d][hw] f32 -> zF fragment order [kb=8][rt=1024][lane=64][8] bf16.
__global__ __launch_bounds__(256) void vq_convz(const float* __restrict__ z,
                                                unsigned short* __restrict__ zF) {
  const int t    = blockIdx.x * 256 + threadIdx.x;
  const int kb   = t >> 16;
  const int rt   = (t >> 6) & 1023;
  const int lane = t & 63;
  const int m  = rt * 16 + (lane & 15);
  const int k0 = kb * 32 + (lane >> 4) * 8;
  const int b  = m >> 10, hw = m & 1023;
  const float* zp = z + ((size_t)b << 18) + hw;
  bhalf8 v;
#pragma unroll
  for (int j = 0; j < 8; ++j)
    v[j] = (short)f2bf(zp[(size_t)(k0 + j) << 10]);
  *reinterpret_cast<bhalf8*>(&zF[(size_t)t << 3]) = v;
}

// cb [n][d] f32 -> cbF fragment order [kb=8][ct=512][lane=64][8] bf16.
__global__ __launch_bounds__(256) void vq_convcb(const float* __restrict__ cb,
                                                 unsigned short* __restrict__ cbF) {
  const int t    = blockIdx.x * 256 + threadIdx.x;
  const int kb   = t >> 15;
  const int ct   = (t >> 6) & 511;
  const int lane = t & 63;
  const int col = ct * 16 + (lane & 15);
  const int k0  = kb * 32 + (lane >> 4) * 8;
  const float4 a = *reinterpret_cast<const float4*>(&cb[(size_t)col * kDim + k0]);
  const float4 c = *reinterpret_cast<const float4*>(&cb[(size_t)col * kDim + k0 + 4]);
  bhalf8 v;
  v[0] = (short)f2bf(a.x); v[1] = (short)f2bf(a.y);
  v[2] = (short)f2bf(a.z); v[3] = (short)f2bf(a.w);
  v[4] = (short)f2bf(c.x); v[5] = (short)f2bf(c.y);
  v[6] = (short)f2bf(c.z); v[7] = (short)f2bf(c.w);
  *reinterpret_cast<bhalf8*>(&cbF[(size_t)t << 3]) = v;
}

// Per-row s = sum(z^2), EXACT same f32 op order as the validated R2 kernel.
__global__ __launch_bounds__(256) void vq_rows(const float* __restrict__ z,
                                               float* __restrict__ srow,
                                               u64* __restrict__ pack,
                                               unsigned* __restrict__ cnt) {
  const int m  = blockIdx.x * 256 + threadIdx.x;
  const int b  = m >> 10, hw = m & 1023;
  const float* zp = z + ((size_t)b << 18) + hw;
  float r8[8];
#pragma unroll
  for (int j = 0; j < 8; ++j) {
    const float v = zp[(size_t)j << 10];
    r8[j] = __fmul_rn(v, v);
  }
  for (int d = 8; d < kDim; d += 8) {
#pragma unroll
    for (int j = 0; j < 8; ++j) {
      const float v = zp[(size_t)(d + j) << 10];
      r8[j] = __fadd_rn(r8[j], __fmul_rn(v, v));
    }
  }
  srow[m] = __fadd_rn(
      __fadd_rn(__fadd_rn(r8[0], r8[1]), __fadd_rn(r8[2], r8[3])),
      __fadd_rn(__fadd_rn(r8[4], r8[5]), __fadd_rn(r8[6], r8[7])));
  pack[m] = ~0ull;
  if (m == 0) *cnt = 0u;
}

// Single-pass bf16 MFMA GEMM, counted-vmcnt pipeline (T3+T4):
// 4-deep B buffers, raw s_barrier at iter END, per-iter literal vmcnt(N)
// so prefetch loads stay in flight across barriers (never vmcnt(0) mid-loop).
// A-fragments direct from zF (static af[2], no copies -> no early drains).
// Cross-wave safety: wave B's vmcnt@(j-1) forces B's stage(j) before the
// barrier rendezvous that precedes any wave's reads@j.
__global__ __launch_bounds__(256, 2) void vq_gemm1(
    const unsigned short* __restrict__ zF,
    const unsigned short* __restrict__ cbF,
    float4* __restrict__ tt) {
  __shared__ __align__(16) unsigned short Bs[4][4096];  // 8 KB each
  const int tid  = threadIdx.x;
  int mt, nt;
  tile_map(blockIdx.x, mt, nt);
  const int m0   = mt * 256, n0 = nt * 128;
  const int w    = tid >> 6, lane = tid & 63;
  const int r16  = lane & 15, kg = lane >> 4;

  floatx4 acc[4][8];
#pragma unroll
  for (int i = 0; i < 4; ++i)
#pragma unroll
    for (int j = 0; j < 8; ++j) acc[i][j] = floatx4{0.f, 0.f, 0.f, 0.f};

  auto stage = [&](int kb) {  // 2 gload_lds into Bs[kb%4]
    const unsigned short* src = cbF + (((size_t)(kb * 512 + nt * 8)) << 9);
#pragma unroll
    for (int i = 0; i < 2; ++i)
      gload_lds16(src + (((i * 256 + tid)) << 3),
                  &Bs[kb & 3][(i * 256 + w * 64) << 3]);
  };
  const int rtw = mt * 16 + w * 4;
  auto loadA = [&](int kb, bhalf8* af) {  // 4 x 16B coalesced global
#pragma unroll
    for (int mi = 0; mi < 4; ++mi)
      af[mi] = *reinterpret_cast<const bhalf8*>(
          &zF[((size_t)((kb * 1024 + rtw + mi) * 64 + lane)) << 3]);
  };

  bhalf8 af[2][4];
  // Prologue ledger: S(0); A(0); S(1); S(2); vmcnt(8)=after-S(0); barrier.
  stage(0);
  loadA(0, af[0]);
  stage(1);
  stage(2);
  asm volatile("s_waitcnt vmcnt(8)" ::: "memory");
  __builtin_amdgcn_sched_barrier(0);
  __builtin_amdgcn_s_barrier();
  __builtin_amdgcn_sched_barrier(0);

#pragma unroll
  for (int kb = 0; kb < 8; ++kb) {
    if (kb < 7) loadA(kb + 1, af[(kb + 1) & 1]);   // A(kb+1)
    if (kb < 5) stage(kb + 3);                     // S(kb+3)
    // vmcnt = #VMEM issued after A(kb): forces A(kb) and S(kb) (older).
    if (kb == 0)      asm volatile("s_waitcnt vmcnt(10)" ::: "memory");
    else if (kb <= 4) asm volatile("s_waitcnt vmcnt(8)"  ::: "memory");
    else if (kb == 5) asm volatile("s_waitcnt vmcnt(6)"  ::: "memory");
    else if (kb == 6) asm volatile("s_waitcnt vmcnt(4)"  ::: "memory");
    else              asm volatile("s_waitcnt vmcnt(0)"  ::: "memory");
    __builtin_amdgcn_sched_barrier(0);
    bhalf8 bf[8];
#pragma unroll
    for (int ni = 0; ni < 8; ++ni)
      bf[ni] = *reinterpret_cast<const bhalf8*>(
          &Bs[kb & 3][(ni * 64 + lane) << 3]);
#pragma unroll
    for (int mi = 0; mi < 4; ++mi)
#pragma unroll
      for (int ni = 0; ni < 8; ++ni)
        acc[mi][ni] = __builtin_amdgcn_mfma_f32_16x16x32_bf16(
            af[kb & 1][mi], bf[ni], acc[mi][ni], 0, 0, 0);
    if (kb < 7) {  // end-of-iter rendezvous (ds_reads already retired)
      __builtin_amdgcn_sched_barrier(0);
      __builtin_amdgcn_s_barrier();
      __builtin_amdgcn_sched_barrier(0);
    }
  }

  // Per-row top-2 across the 128-code tile.
  // C frag mapping: col = lane&15, row = (lane>>4)*4 + reg.
#pragma unroll
  for (int mi = 0; mi < 4; ++mi)
#pragma unroll
    for (int reg = 0; reg < 4; ++reg) {
      float a1 = acc[mi][0][reg];
      int   i1 = n0 + r16;
      float a2 = -3.4e38f;
      int   i2 = 0x7fffffff;
#pragma unroll
      for (int ni = 1; ni < 8; ++ni) {
        const float v = acc[mi][ni][reg];
        const int  ix = n0 + ni * 16 + r16;
        if (lexgt(v, ix, a1, i1)) { a2 = a1; i2 = i1; a1 = v; i1 = ix; }
        else if (lexgt(v, ix, a2, i2)) { a2 = v; i2 = ix; }
      }
#pragma unroll
      for (int off = 1; off < 16; off <<= 1) {
        const float b1 = __shfl_xor(a1, off);
        const int   j1 = __shfl_xor(i1, off);
        const float b2 = __shfl_xor(a2, off);
        const int   j2 = __shfl_xor(i2, off);
        if (lexgt(b1, j1, a1, i1)) {
          if (lexgt(b2, j2, a1, i1)) { a2 = b2; i2 = j2; }
          else                       { a2 = a1; i2 = i1; }
          a1 = b1; i1 = j1;
        } else if (lexgt(b1, j1, a2, i2)) {
          a2 = b1; i2 = j1;
        }
      }
      if (r16 == 0) {
        const int row = m0 + w * 64 + mi * 16 + kg * 4 + reg;
        tt[(size_t)nt * kRows + row] =
            make_float4(a1, __int_as_float(i1), a2, __int_as_float(i2));
      }
    }
}

// Merge: global row-max over tile top-1s; emit within-margin candidates.
// Tile whose 2nd-best is also within margin -> flag for wave-level rescan.
__global__ __launch_bounds__(256) void vq_mrg(const float4* __restrict__ tt,
                                              u64* __restrict__ list,
                                              unsigned* __restrict__ cnt) {
  const int m = blockIdx.x * 256 + threadIdx.x;
  float M = -3.4e38f;
  for (int nt = 0; nt < kNT; ++nt)
    M = fmaxf(M, tt[(size_t)nt * kRows + m].x);
  const float t = M - kMargin;
  for (int nt = 0; nt < kNT; ++nt) {
    const float4 e = tt[(size_t)nt * kRows + m];
    if (e.z > t) {
      const unsigned slot = atomicAdd(cnt, 1u);
      if (slot < kCap)
        list[slot] = ((u64)(unsigned)m << 32) | 0x80000000u | (unsigned)nt;
    } else if (e.x > t) {
      const unsigned slot = atomicAdd(cnt, 1u);
      if (slot < kCap)
        list[slot] = ((u64)(unsigned)m << 32) | (unsigned)__float_as_int(e.y);
    }
  }
}

// Exact f32 rescore core (bit-identical to R2 numerics): sequential
// ascending-k fmaf chain, dv = fl32(s - 2*dot); lex-min via u64 atomicMin.
__device__ inline void rescore_one(const float* __restrict__ z,
                                   const float* __restrict__ cb,
                                   const float* __restrict__ srow,
                                   u64* __restrict__ pack, int m, int code) {
  const int b = m >> 10, hw = m & 1023;
  const float* zr = z + ((size_t)b << 18) + hw;
  const float* er = cb + (size_t)code * kDim;
  float d = 0.f;
  for (int k = 0; k < kDim; ++k)
    d = fmaf(zr[(size_t)k << 10], er[k], d);
  const float dv = __fsub_rn(srow[m], 2.0f * d);
  atomicMin(pack + m, ((u64)__float_as_uint(dv) << 32) | (unsigned)code);
}

// Wave-level rescore: flagged tiles use all 64 lanes (2 codes each);
// singles on lane 0. Per-code numerics unchanged (bit-exact).
__global__ __launch_bounds__(256) void vq_rescoreW(
    const float* __restrict__ z, const float* __restrict__ cb,
    const float* __restrict__ srow, const u64* __restrict__ list,
    const unsigned* __restrict__ cnt, u64* __restrict__ pack) {
  const unsigned total = min(*cnt, kCap);
  const int lane = threadIdx.x & 63;
  const unsigned wid = (blockIdx.x * 256 + threadIdx.x) >> 6;
  const unsigned nw  = gridDim.x * 4;
  for (unsigned i = wid; i < total; i += nw) {
    const u64 e = list[i];
    const int m = (int)(e >> 32);
    const unsigned low = (unsigned)(e & 0xffffffffu);
    if (low & 0x80000000u) {
      const int c0 = (int)(low & 63) * 128;
      rescore_one(z, cb, srow, pack, m, c0 + lane);
      rescore_one(z, cb, srow, pack, m, c0 + 64 + lane);
    } else if (lane == 0) {
      rescore_one(z, cb, srow, pack, m, (int)low);
    }
  }
}

// Per-thread rescore (mid path; singles only there).
__global__ __launch_bounds__(256) void vq_rescore(
    const float* __restrict__ z, const float* __restrict__ cb,
    const float* __restrict__ srow, const u64* __restrict__ list,
    const unsigned* __restrict__ cnt, u64* __restrict__ pack) {
  const unsigned total = min(*cnt, kCap);
  for (unsigned i = blockIdx.x * 256 + threadIdx.x; i < total;
       i += gridDim.x * 256) {
    const u64 e = list[i];
    rescore_one(z, cb, srow, pack, (int)(e >> 32), (int)(e & 0x7fffffffu));
  }
}

// Gather z_q to [B,C,H,W], idx output, f64 loss partials.
__global__ __launch_bounds__(256) void vq_out2(
    const float* __restrict__ z, const float* __restrict__ cb,
    const u64* __restrict__ pack, float* __restrict__ out,
    double* __restrict__ bloss) {
  __shared__ double wsum[4];
  const int tid  = threadIdx.x;
  const int lane = tid & 63;
  const int wv   = tid >> 6;
  const int m    = blockIdx.x * 4 + wv;
  const int b    = m >> 10;
  const int hw   = m & 1023;
  const u64 p = pack[m];
  const int best = (p == ~0ull) ? 0 : (int)(p & 0x7fffffffu);
  const float* zr = z + ((size_t)b << 18) + hw;
  const float* e  = cb + (size_t)best * kDim;
  float* o0 = out + ((size_t)b << 18) + hw;
  double acc = 0;
#pragma unroll
  for (int j = 0; j < 4; ++j) {
    const int d = lane + j * 64;
    const float ev = e[d];
    const float zv = zr[(size_t)d << 10];
    o0[(size_t)d << 10] = ev;
    const double diff = (double)ev - (double)zv;
    acc += diff * diff;
  }
#pragma unroll
  for (int off = 32; off > 0; off >>= 1) acc += __shfl_xor(acc, off);
  if (lane == 0) {
    out[kOutIdx + m] = (float)best;
    wsum[wv] = acc;
  }
  __syncthreads();
  if (tid == 0) bloss[blockIdx.x] = wsum[0] + wsum[1] + wsum[2] + wsum[3];
}

__global__ __launch_bounds__(256) void vq_final(
    const double* __restrict__ bloss, float* __restrict__ out) {
  __shared__ double sm[256];
  double s = 0;
  for (int i = threadIdx.x; i < kRows / 4; i += 256) s += bloss[i];
  sm[threadIdx.x] = s;
  __syncthreads();
  for (int st = 128; st > 0; st >>= 1) {
    if (threadIdx.x < st) sm[threadIdx.x] += sm[threadIdx.x + st];
    __syncthreads();
  }
  if (threadIdx.x == 0)
    out[kOutLoss] = (float)(1.25 * sm[0] / (double)kOutZq);
}

// ---------------- mid fallback: R5 two-phase (proven structure) ----------

template <int PHASE>
__global__ __launch_bounds__(256, 2) void vq_gemm2(
    const unsigned short* __restrict__ zF,
    const unsigned short* __restrict__ cbF,
    const float* __restrict__ rowmax, float* __restrict__ rowmaxp,
    u64* __restrict__ list, unsigned* __restrict__ cnt) {
  __shared__ __align__(16) unsigned short Bs[2][4096];
  const int tid  = threadIdx.x;
  int mt, nt;
  tile_map(blockIdx.x, mt, nt);
  const int m0   = mt * 256, n0 = nt * 128;
  const int w    = tid >> 6, lane = tid & 63;
  const int r16  = lane & 15, kg = lane >> 4;

  floatx4 acc[4][8];
#pragma unroll
  for (int i = 0; i < 4; ++i)
#pragma unroll
    for (int j = 0; j < 8; ++j) acc[i][j] = floatx4{0.f, 0.f, 0.f, 0.f};

  auto stage = [&](int kb, int buf) {
    const unsigned short* src = cbF + (((size_t)(kb * 512 + nt * 8)) << 9);
#pragma unroll
    for (int i = 0; i < 2; ++i)
      gload_lds16(src + (((i * 256 + tid)) << 3),
                  &Bs[buf][(i * 256 + w * 64) << 3]);
  };
  const int rtw = mt * 16 + w * 4;
  auto loadA = [&](int kb, bhalf8* af) {
#pragma unroll
    for (int mi = 0; mi < 4; ++mi)
      af[mi] = *reinterpret_cast<const bhalf8*>(
          &zF[((size_t)((kb * 1024 + rtw + mi) * 64 + lane)) << 3]);
  };

  bhalf8 afc[4], afn[4];
  stage(0, 0);
  loadA(0, afc);
  __syncthreads();

#pragma unroll
  for (int kb = 0; kb < 8; ++kb) {
    const int cur = kb & 1;
    if (kb < 7) {
      stage(kb + 1, cur ^ 1);
      loadA(kb + 1, afn);
    }
    bhalf8 bf[8];
#pragma unroll
    for (int ni = 0; ni < 8; ++ni)
      bf[ni] = *reinterpret_cast<const bhalf8*>(&Bs[cur][(ni * 64 + lane) << 3]);
#pragma unroll
    for (int mi = 0; mi < 4; ++mi)
#pragma unroll
      for (int ni = 0; ni < 8; ++ni)
        acc[mi][ni] = __builtin_amdgcn_mfma_f32_16x16x32_bf16(
            afc[mi], bf[ni], acc[mi][ni], 0, 0, 0);
    __syncthreads();
#pragma unroll
    for (int mi = 0; mi < 4; ++mi) afc[mi] = afn[mi];
  }

  if (PHASE == 0) {
#pragma unroll
    for (int mi = 0; mi < 4; ++mi)
#pragma unroll
      for (int reg = 0; reg < 4; ++reg) {
        float v = acc[mi][0][reg];
#pragma unroll
        for (int ni = 1; ni < 8; ++ni) v = fmaxf(v, acc[mi][ni][reg]);
#pragma unroll
        for (int off = 1; off < 16; off <<= 1) v = fmaxf(v, __shfl_xor(v, off));
        if (r16 == 0)
          rowmaxp[(size_t)nt * kRows + m0 + w * 64 + mi * 16 + kg * 4 + reg] = v;
      }
  } else {
#pragma unroll
    for (int mi = 0; mi < 4; ++mi)
#pragma unroll
      for (int reg = 0; reg < 4; ++reg) {
        const int row = m0 + w * 64 + mi * 16 + kg * 4 + reg;
        const float t = rowmax[row] - kMargin;
#pragma unroll
        for (int ni = 0; ni < 8; ++ni) {
          if (acc[mi][ni][reg] > t) {
            const unsigned slot = atomicAdd(cnt, 1u);
            if (slot < kCap)
              list[slot] = ((u64)(unsigned)row << 32) |
                           (unsigned)(n0 + ni * 16 + r16);
          }
        }
      }
  }
}

__global__ __launch_bounds__(256) void vq_rmax(const float* __restrict__ rowmaxp,
                                               float* __restrict__ rowmax) {
  const int m = blockIdx.x * 256 + threadIdx.x;
  float v = rowmaxp[m];
  for (int s = 1; s < kNT; ++s) v = fmaxf(v, rowmaxp[(size_t)s * kRows + m]);
  rowmax[m] = v;
}

extern "C" void kernel_launch(void* const* d_in, const int* in_sizes, int n_in,
                              void* d_out, int out_size, void* d_ws, size_t ws_size,
                              hipStream_t stream) {
  const float* z  = (const float*)d_in[0];
  const float* cb = (const float*)d_in[1];
  float* out = (float*)d_out;

  unsigned short* zF  = (unsigned short*)((char*)d_ws + kOffZf);
  unsigned short* cbF = (unsigned short*)((char*)d_ws + kOffCbf);

  if (ws_size >= kWsFast) {
    float*    srow  = (float*)((char*)d_ws + kOffSrow);
    float4*   tt    = (float4*)((char*)d_ws + kOffTt);
    u64*      pack  = (u64*)((char*)d_ws + kOffPack);
    u64*      list  = (u64*)((char*)d_ws + kOffList);
    unsigned* cnt   = (unsigned*)((char*)d_ws + kOffCnt);
    double*   bloss = (double*)((char*)d_ws + kOffBloss);

    vq_convz   <<<2048, 256, 0, stream>>>(z, zF);
    vq_convcb  <<<1024, 256, 0, stream>>>(cb, cbF);
    vq_rows    <<<kRows / 256, 256, 0, stream>>>(z, srow, pack, cnt);
    vq_gemm1   <<<4096, 256, 0, stream>>>(zF, cbF, tt);
    vq_mrg     <<<kRows / 256, 256, 0, stream>>>(tt, list, cnt);
    vq_rescoreW<<<256, 256, 0, stream>>>(z, cb, srow, list, cnt, pack);
    vq_out2    <<<kRows / 4, 256, 0, stream>>>(z, cb, pack, out, bloss);
    vq_final   <<<1, 256, 0, stream>>>(bloss, out);
  } else {
    float*    srow    = (float*)((char*)d_ws + kM_Srow);
    float*    rowmax  = (float*)((char*)d_ws + kM_Rmax);
    float*    rowmaxp = (float*)((char*)d_ws + kM_RmaxP);
    u64*      pack    = (u64*)((char*)d_ws + kM_Pack);
    u64*      list    = (u64*)((char*)d_ws + kM_List);
    unsigned* cnt     = (unsigned*)((char*)d_ws + kM_Cnt);
    double*   bloss   = (double*)((char*)d_ws + kM_Bloss);

    vq_convz  <<<2048, 256, 0, stream>>>(z, zF);
    vq_convcb <<<1024, 256, 0, stream>>>(cb, cbF);
    vq_rows   <<<kRows / 256, 256, 0, stream>>>(z, srow, pack, cnt);
    vq_gemm2<0><<<4096, 256, 0, stream>>>(zF, cbF, rowmax, rowmaxp, list, cnt);
    vq_rmax   <<<kRows / 256, 256, 0, stream>>>(rowmaxp, rowmax);
    vq_gemm2<1><<<4096, 256, 0, stream>>>(zF, cbF, rowmax, rowmaxp, list, cnt);
    vq_rescore<<<256, 256, 0, stream>>>(z, cb, srow, list, cnt, pack);
    vq_out2   <<<kRows / 4, 256, 0, stream>>>(z, cb, pack, out, bloss);
    vq_final  <<<1, 256, 0, stream>>>(bloss, out);
  }
}

// Round 8
// 360.992 us; speedup vs baseline: 3.4852x; 1.5895x over previous
//
#include <hip/hip_runtime.h>

typedef short  bhalf8  __attribute__((ext_vector_type(8)));
typedef float  floatx4 __attribute__((ext_vector_type(4)));
typedef unsigned long long u64;

namespace {
constexpr int kDim   = 256;
constexpr int kCodes = 8192;
constexpr int kRows  = 16384;   // 16 * 32 * 32
constexpr int kOutZq   = 16 * 256 * 32 * 32;  // 4194304
constexpr int kOutLoss = kOutZq;
constexpr int kOutIdx  = kOutZq + 1;
constexpr int kNT = 32;                        // 256-code tiles
constexpr unsigned kCapS = 131072, kCapF = 32768;
constexpr float kMargin = 4e-5f;  // half-bin 1.53e-5 + approx-err tail (validated R4-R7)

// ws layout (bytes). zT (16 MB, f32 [m][k]) is written AFTER mrg and
// overlaps the then-dead zF+cbF+tt[0:4MB] region.
constexpr size_t kOffZf    = 0;                                     // 8 MB
constexpr size_t kOffCbf   = kOffZf   + (size_t)kRows  * kDim * 2;  // 4 MB
constexpr size_t kOffTt    = kOffCbf  + (size_t)kCodes * kDim * 2;  // 8 MB
constexpr size_t kOffZt    = 0;                                     // 16 MB overlay
constexpr size_t kOffSrow  = kOffTt   + (size_t)kNT * kRows * 16;   // 20 MB
constexpr size_t kOffPack  = kOffSrow + (size_t)kRows * 4;
constexpr size_t kOffListS = kOffPack + (size_t)kRows * 8;
constexpr size_t kOffListF = kOffListS + (size_t)kCapS * 8;
constexpr size_t kOffCnt   = kOffListF + (size_t)kCapF * 8;
constexpr size_t kOffBloss = kOffCnt  + 256;
constexpr size_t kWsNeed   = kOffBloss + (size_t)(kRows / 4) * 8;   // ~22.5 MB
}

__device__ inline unsigned short f2bf(float f) {  // RNE f32 -> bf16
  unsigned u = __float_as_uint(f);
  u += 0x7fffu + ((u >> 16) & 1u);
  return (unsigned short)(u >> 16);
}

__device__ inline void gload_lds16(const void* g, void* l) {
  __builtin_amdgcn_global_load_lds(
      (const __attribute__((address_space(1))) unsigned int*)(g),
      (__attribute__((address_space(3))) unsigned int*)(l), 16, 0, 0);
}

__device__ inline bool lexgt(float v, int iv, float w, int iw) {
  return v > w || (v == w && iv < iw);
}

// z [b][d][hw] f32 -> zF fragment order [kb=8][rt=1024][lane=64][8] bf16.
__global__ __launch_bounds__(256) void vq_convz(const float* __restrict__ z,
                                                unsigned short* __restrict__ zF) {
  const int t    = blockIdx.x * 256 + threadIdx.x;
  const int kb   = t >> 16;
  const int rt   = (t >> 6) & 1023;
  const int lane = t & 63;
  const int m  = rt * 16 + (lane & 15);
  const int k0 = kb * 32 + (lane >> 4) * 8;
  const int b  = m >> 10, hw = m & 1023;
  const float* zp = z + ((size_t)b << 18) + hw;
  bhalf8 v;
#pragma unroll
  for (int j = 0; j < 8; ++j)
    v[j] = (short)f2bf(zp[(size_t)(k0 + j) << 10]);
  *reinterpret_cast<bhalf8*>(&zF[(size_t)t << 3]) = v;
}

// cb [n][d] f32 -> cbF fragment order [kb=8][ct=512][lane=64][8] bf16.
__global__ __launch_bounds__(256) void vq_convcb(const float* __restrict__ cb,
                                                 unsigned short* __restrict__ cbF) {
  const int t    = blockIdx.x * 256 + threadIdx.x;
  const int kb   = t >> 15;
  const int ct   = (t >> 6) & 511;
  const int lane = t & 63;
  const int col = ct * 16 + (lane & 15);
  const int k0  = kb * 32 + (lane >> 4) * 8;
  const float4 a = *reinterpret_cast<const float4*>(&cb[(size_t)col * kDim + k0]);
  const float4 c = *reinterpret_cast<const float4*>(&cb[(size_t)col * kDim + k0 + 4]);
  bhalf8 v;
  v[0] = (short)f2bf(a.x); v[1] = (short)f2bf(a.y);
  v[2] = (short)f2bf(a.z); v[3] = (short)f2bf(a.w);
  v[4] = (short)f2bf(c.x); v[5] = (short)f2bf(c.y);
  v[6] = (short)f2bf(c.z); v[7] = (short)f2bf(c.w);
  *reinterpret_cast<bhalf8*>(&cbF[(size_t)t << 3]) = v;
}

// Per-row s = sum(z^2), EXACT same f32 op order as the validated R2 kernel.
__global__ __launch_bounds__(256) void vq_rows(const float* __restrict__ z,
                                               float* __restrict__ srow,
                                               u64* __restrict__ pack,
                                               unsigned* __restrict__ cnts) {
  const int m  = blockIdx.x * 256 + threadIdx.x;
  const int b  = m >> 10, hw = m & 1023;
  const float* zp = z + ((size_t)b << 18) + hw;
  float r8[8];
#pragma unroll
  for (int j = 0; j < 8; ++j) {
    const float v = zp[(size_t)j << 10];
    r8[j] = __fmul_rn(v, v);
  }
  for (int d = 8; d < kDim; d += 8) {
#pragma unroll
    for (int j = 0; j < 8; ++j) {
      const float v = zp[(size_t)(d + j) << 10];
      r8[j] = __fadd_rn(r8[j], __fmul_rn(v, v));
    }
  }
  srow[m] = __fadd_rn(
      __fadd_rn(__fadd_rn(r8[0], r8[1]), __fadd_rn(r8[2], r8[3])),
      __fadd_rn(__fadd_rn(r8[4], r8[5]), __fadd_rn(r8[6], r8[7])));
  pack[m] = ~0ull;
  if (m == 0) { cnts[0] = 0u; cnts[1] = 0u; }
}

// Transposed-role bf16 MFMA GEMM: A = codes (cbF, direct global, per-wave
// distinct), B = zrows (zF via 4KB/kb LDS dbuf). Block = 256 codes x 64
// zrows, 4 waves (wave w: codes w*64..+64). acc 4x4x4 = 64 VGPR ->
// __launch_bounds__(256,3) = 12 waves/CU (TLP hides latency, m97-style).
// C frag: row=code=(lane>>4)*4+reg, col=zrow=lane&15 -> per-lane values are
// codes of ONE zrow -> cheap top-2 (15 lexgt + 2 shfl steps + LDS merge).
// Scores bit-identical to R4-R7 (same per-dot MFMA sum, same kb order).
__global__ __launch_bounds__(256, 3) void vq_gemmT(
    const unsigned short* __restrict__ zF,
    const unsigned short* __restrict__ cbF,
    float4* __restrict__ tt) {
  __shared__ __align__(16) unsigned short Bs[2][2048];  // 4 KB each
  __shared__ float4 wtop[4][64];
  const int tid  = threadIdx.x;
  const int xcd  = blockIdx.x & 7, slot = blockIdx.x >> 3;
  const int nt   = xcd * 4 + (slot & 3);   // XCD-resident 512KB cbF slice
  const int mt   = slot >> 2;              // zrow tile (64 rows)
  const int w    = tid >> 6, lane = tid & 63;
  const int r16  = lane & 15, kg = lane >> 4;

  floatx4 acc[4][4];
#pragma unroll
  for (int i = 0; i < 4; ++i)
#pragma unroll
    for (int j = 0; j < 4; ++j) acc[i][j] = floatx4{0.f, 0.f, 0.f, 0.f};

  auto stage = [&](int kb, int buf) {  // 4KB zF tile (4 rt-frags), 1 op/thread
    const unsigned short* src = zF + (((size_t)(kb * 1024 + mt * 4)) << 9);
    gload_lds16(src + ((size_t)(w * 64 + lane) << 3), &Bs[buf][(w * 64) << 3]);
  };
  auto loadA = [&](int kb, bhalf8* af) {  // 4 x 16B coalesced global (cbF)
    const size_t base = (size_t)(kb * 512 + nt * 16 + w * 4);
#pragma unroll
    for (int mi = 0; mi < 4; ++mi)
      af[mi] = *reinterpret_cast<const bhalf8*>(
          &cbF[((base + mi) * 64 + lane) << 3]);
  };

  bhalf8 af[2][4];
  stage(0, 0);
  loadA(0, af[0]);
  __syncthreads();

#pragma unroll
  for (int kb = 0; kb < 8; ++kb) {
    if (kb < 7) {
      stage(kb + 1, (kb + 1) & 1);
      loadA(kb + 1, af[(kb + 1) & 1]);
    }
    bhalf8 bf[4];
#pragma unroll
    for (int ni = 0; ni < 4; ++ni)
      bf[ni] = *reinterpret_cast<const bhalf8*>(
          &Bs[kb & 1][(ni * 64 + lane) << 3]);
#pragma unroll
    for (int mi = 0; mi < 4; ++mi)
#pragma unroll
      for (int ni = 0; ni < 4; ++ni)
        acc[mi][ni] = __builtin_amdgcn_mfma_f32_16x16x32_bf16(
            af[kb & 1][mi], bf[ni], acc[mi][ni], 0, 0, 0);
    __syncthreads();
  }

  auto merge2 = [&](float& a1, int& i1, float& a2, int& i2,
                    float b1, int j1, float b2, int j2) {
    if (lexgt(b1, j1, a1, i1)) {
      if (lexgt(b2, j2, a1, i1)) { a2 = b2; i2 = j2; }
      else                       { a2 = a1; i2 = i1; }
      a1 = b1; i1 = j1;
    } else if (lexgt(b1, j1, a2, i2)) {
      a2 = b1; i2 = j1;
    }
  };

  // Per-wave top-2 over its 64 codes, per zrow (in-lane + 2 shfl steps).
#pragma unroll
  for (int ni = 0; ni < 4; ++ni) {
    float a1 = -3.4e38f, a2 = -3.4e38f;
    int   i1 = 0x7fffffff, i2 = 0x7fffffff;
#pragma unroll
    for (int mi = 0; mi < 4; ++mi)
#pragma unroll
      for (int reg = 0; reg < 4; ++reg) {
        const float v = acc[mi][ni][reg];
        const int  ix = nt * 256 + w * 64 + mi * 16 + kg * 4 + reg;
        if (lexgt(v, ix, a1, i1)) { a2 = a1; i2 = i1; a1 = v; i1 = ix; }
        else if (lexgt(v, ix, a2, i2)) { a2 = v; i2 = ix; }
      }
#pragma unroll
    for (int off = 16; off < 64; off <<= 1) {
      const float b1 = __shfl_xor(a1, off);
      const int   j1 = __shfl_xor(i1, off);
      const float b2 = __shfl_xor(a2, off);
      const int   j2 = __shfl_xor(i2, off);
      merge2(a1, i1, a2, i2, b1, j1, b2, j2);
    }
    if (kg == 0)
      wtop[w][ni * 16 + r16] = make_float4(a1, __int_as_float(i1),
                                           a2, __int_as_float(i2));
  }
  __syncthreads();
  // Block merge: 4 wave-quarters (64 codes each) -> top-2 over 256 codes.
  if (tid < 64) {
    float4 e = wtop[0][tid];
    float a1 = e.x, a2 = e.z;
    int   i1 = __float_as_int(e.y), i2 = __float_as_int(e.w);
#pragma unroll
    for (int q = 1; q < 4; ++q) {
      e = wtop[q][tid];
      merge2(a1, i1, a2, i2, e.x, __float_as_int(e.y), e.z, __float_as_int(e.w));
    }
    tt[(size_t)nt * kRows + mt * 64 + tid] =
        make_float4(a1, __int_as_float(i1), a2, __int_as_float(i2));
  }
}

// Merge: global row-max over tile top-1s; singles to listS; tiles whose
// 2nd-best is also within margin -> listF (full-tile exact rescan).
__global__ __launch_bounds__(256) void vq_mrg(const float4* __restrict__ tt,
                                              u64* __restrict__ listS,
                                              u64* __restrict__ listF,
                                              unsigned* __restrict__ cnts) {
  const int m = blockIdx.x * 256 + threadIdx.x;
  float M = -3.4e38f;
  for (int nt = 0; nt < kNT; ++nt)
    M = fmaxf(M, tt[(size_t)nt * kRows + m].x);
  const float t = M - kMargin;
  for (int nt = 0; nt < kNT; ++nt) {
    const float4 e = tt[(size_t)nt * kRows + m];
    if (e.z > t) {
      const unsigned slot = atomicAdd(&cnts[1], 1u);
      if (slot < kCapF)
        listF[slot] = ((u64)(unsigned)m << 32) | (unsigned)nt;
    } else if (e.x > t) {
      const unsigned slot = atomicAdd(&cnts[0], 1u);
      if (slot < kCapS)
        listS[slot] = ((u64)(unsigned)m << 32) | (unsigned)__float_as_int(e.y);
    }
  }
}

// z [b][d][hw] -> zT [m][k] f32 (LDS-tiled transpose; contiguous rescore rows).
__global__ __launch_bounds__(256) void vq_trz(const float* __restrict__ z,
                                              float* __restrict__ zT) {
  __shared__ float t[64][65];
  const int m0 = blockIdx.x * 64;
  const int d0 = blockIdx.y * 64;
  const int b  = m0 >> 10;
  const int hw0 = m0 & 1023;
  const int tx = threadIdx.x & 15;
  const int r  = threadIdx.x >> 4;
  const float* zp = z + ((size_t)b << 18) + hw0;
  for (int rr = r; rr < 64; rr += 16) {
    const float4 v = *reinterpret_cast<const float4*>(
        &zp[((size_t)(d0 + rr) << 10) + tx * 4]);
    t[tx * 4 + 0][rr] = v.x; t[tx * 4 + 1][rr] = v.y;
    t[tx * 4 + 2][rr] = v.z; t[tx * 4 + 3][rr] = v.w;
  }
  __syncthreads();
  for (int rr = r; rr < 64; rr += 16) {
    float4 w;
    w.x = t[rr][tx * 4 + 0]; w.y = t[rr][tx * 4 + 1];
    w.z = t[rr][tx * 4 + 2]; w.w = t[rr][tx * 4 + 3];
    *reinterpret_cast<float4*>(&zT[(size_t)(m0 + rr) * kDim + d0 + tx * 4]) = w;
  }
}

// Exact f32 rescore (bit-identical chain: ascending-k fmaf, zT values == z).
__device__ inline void rescore_oneT(const float* __restrict__ zT,
                                    const float* __restrict__ cb,
                                    const float* __restrict__ srow,
                                    u64* __restrict__ pack, int m, int code) {
  const float* zr = zT + (size_t)m * kDim;
  const float* er = cb + (size_t)code * kDim;
  float d = 0.f;
  for (int k = 0; k < kDim; ++k) d = fmaf(zr[k], er[k], d);
  const float dv = __fsub_rn(srow[m], 2.0f * d);
  atomicMin(pack + m, ((u64)__float_as_uint(dv) << 32) | (unsigned)code);
}

// Singles: one per thread, grid-stride (fully parallel).
__global__ __launch_bounds__(256) void vq_resS(
    const float* __restrict__ zT, const float* __restrict__ cb,
    const float* __restrict__ srow, const u64* __restrict__ listS,
    const unsigned* __restrict__ cnts, u64* __restrict__ pack) {
  const unsigned total = min(cnts[0], kCapS);
  for (unsigned i = blockIdx.x * 256 + threadIdx.x; i < total;
       i += gridDim.x * 256) {
    const u64 e = listS[i];
    rescore_oneT(zT, cb, srow, pack, (int)(e >> 32), (int)(e & 0xffffffffu));
  }
}

// Flagged tiles: one wave per tile; 4 codes/lane, fused ILP chains.
__global__ __launch_bounds__(256) void vq_resF(
    const float* __restrict__ zT, const float* __restrict__ cb,
    const float* __restrict__ srow, const u64* __restrict__ listF,
    const unsigned* __restrict__ cnts, u64* __restrict__ pack) {
  const unsigned total = min(cnts[1], kCapF);
  const int lane = threadIdx.x & 63;
  const unsigned wid = (blockIdx.x * 256 + threadIdx.x) >> 6;
  const unsigned nw  = gridDim.x * 4;
  for (unsigned i = wid; i < total; i += nw) {
    const u64 e = listF[i];
    const int m  = (int)(e >> 32);
    const int c0 = (int)(e & 0xffffffffu) * 256 + lane;
    const float* zr = zT + (size_t)m * kDim;
    const float* e0 = cb + (size_t)(c0 +   0) * kDim;
    const float* e1 = cb + (size_t)(c0 +  64) * kDim;
    const float* e2 = cb + (size_t)(c0 + 128) * kDim;
    const float* e3 = cb + (size_t)(c0 + 192) * kDim;
    float d0 = 0.f, d1 = 0.f, d2 = 0.f, d3 = 0.f;
    for (int k = 0; k < kDim; ++k) {
      const float zv = zr[k];
      d0 = fmaf(zv, e0[k], d0); d1 = fmaf(zv, e1[k], d1);
      d2 = fmaf(zv, e2[k], d2); d3 = fmaf(zv, e3[k], d3);
    }
    const float s = srow[m];
    atomicMin(pack + m, ((u64)__float_as_uint(__fsub_rn(s, 2.0f * d0)) << 32) | (unsigned)(c0));
    atomicMin(pack + m, ((u64)__float_as_uint(__fsub_rn(s, 2.0f * d1)) << 32) | (unsigned)(c0 + 64));
    atomicMin(pack + m, ((u64)__float_as_uint(__fsub_rn(s, 2.0f * d2)) << 32) | (unsigned)(c0 + 128));
    atomicMin(pack + m, ((u64)__float_as_uint(__fsub_rn(s, 2.0f * d3)) << 32) | (unsigned)(c0 + 192));
  }
}

// Gather z_q to [B,C,H,W], idx output, f64 loss partials (zT contiguous reads).
__global__ __launch_bounds__(256) void vq_out2(
    const float* __restrict__ zT, const float* __restrict__ cb,
    const u64* __restrict__ pack, float* __restrict__ out,
    double* __restrict__ bloss) {
  __shared__ double wsum[4];
  const int tid  = threadIdx.x;
  const int lane = tid & 63;
  const int wv   = tid >> 6;
  const int m    = blockIdx.x * 4 + wv;
  const int b    = m >> 10;
  const int hw   = m & 1023;
  const u64 p = pack[m];
  const int best = (p == ~0ull) ? 0 : (int)(p & 0x7fffffffu);
  const float* zr = zT + (size_t)m * kDim;
  const float* e  = cb + (size_t)best * kDim;
  float* o0 = out + ((size_t)b << 18) + hw;
  double acc = 0;
#pragma unroll
  for (int j = 0; j < 4; ++j) {
    const int d = lane + j * 64;
    const float ev = e[d];
    const float zv = zr[d];
    o0[(size_t)d << 10] = ev;
    const double diff = (double)ev - (double)zv;
    acc += diff * diff;
  }
#pragma unroll
  for (int off = 32; off > 0; off >>= 1) acc += __shfl_xor(acc, off);
  if (lane == 0) {
    out[kOutIdx + m] = (float)best;
    wsum[wv] = acc;
  }
  __syncthreads();
  if (tid == 0) bloss[blockIdx.x] = wsum[0] + wsum[1] + wsum[2] + wsum[3];
}

__global__ __launch_bounds__(256) void vq_final(
    const double* __restrict__ bloss, float* __restrict__ out) {
  __shared__ double sm[256];
  double s = 0;
  for (int i = threadIdx.x; i < kRows / 4; i += 256) s += bloss[i];
  sm[threadIdx.x] = s;
  __syncthreads();
  for (int st = 128; st > 0; st >>= 1) {
    if (threadIdx.x < st) sm[threadIdx.x] += sm[threadIdx.x + st];
    __syncthreads();
  }
  if (threadIdx.x == 0)
    out[kOutLoss] = (float)(1.25 * sm[0] / (double)kOutZq);
}

// ---------------- fallback path (verbatim Round-2, proven; 96 KB ws) ------

__global__ __launch_bounds__(256) void vq_pass1s(
    const float* __restrict__ z, const float* __restrict__ cb,
    int* __restrict__ cand) {
  __shared__ __align__(16) float As[kDim * 64];
  __shared__ __align__(16) float Bs[32 * 64];
  __shared__ float Ss[64];
  const int tid = threadIdx.x;
  const int m0  = blockIdx.x * 64;
  {
    const int r  = tid & 63;
    const int d0 = tid >> 6;
    const int n  = m0 + r;
    const int b  = n >> 10;
    const int hw = n & 1023;
    const float* zp = z + ((size_t)b << 18) + hw;
    for (int j = 0; j < 64; ++j) {
      const int d = d0 + (j << 2);
      As[d * 64 + r] = zp[(size_t)d << 10];
    }
  }
  __syncthreads();
  if (tid < 64) {
    float r8[8];
#pragma unroll
    for (int j = 0; j < 8; ++j) {
      const float v = As[j * 64 + tid];
      r8[j] = __fmul_rn(v, v);
    }
    for (int d = 8; d < kDim; d += 8) {
#pragma unroll
      for (int j = 0; j < 8; ++j) {
        const float v = As[(d + j) * 64 + tid];
        r8[j] = __fadd_rn(r8[j], __fmul_rn(v, v));
      }
    }
    Ss[tid] = __fadd_rn(
        __fadd_rn(__fadd_rn(r8[0], r8[1]), __fadd_rn(r8[2], r8[3])),
        __fadd_rn(__fadd_rn(r8[4], r8[5]), __fadd_rn(r8[6], r8[7])));
  }
  __syncthreads();
  const int tx = tid & 15;
  const int ty = tid >> 4;
  float srw[4];
#pragma unroll
  for (int i = 0; i < 4; ++i) srw[i] = Ss[ty * 4 + i];
  float bd[4]; int bi[4];
#pragma unroll
  for (int i = 0; i < 4; ++i) { bd[i] = 3.4e38f; bi[i] = 0; }
  for (int n0 = 0; n0 < kCodes; n0 += 64) {
    float acc[4][4];
#pragma unroll
    for (int i = 0; i < 4; ++i)
#pragma unroll
      for (int j = 0; j < 4; ++j) acc[i][j] = 0.f;
    for (int kc = 0; kc < kDim / 32; ++kc) {
      __syncthreads();
#pragma unroll
      for (int rep = 0; rep < 2; ++rep) {
        const int s  = tid + rep * 256;
        const int c  = s >> 3;
        const int fo = (s & 7) << 2;
        const float4 v = *reinterpret_cast<const float4*>(
            &cb[(size_t)(n0 + c) * kDim + kc * 32 + fo]);
        Bs[(fo + 0) * 64 + c] = v.x;
        Bs[(fo + 1) * 64 + c] = v.y;
        Bs[(fo + 2) * 64 + c] = v.z;
        Bs[(fo + 3) * 64 + c] = v.w;
      }
      __syncthreads();
#pragma unroll
      for (int kk = 0; kk < 32; ++kk) {
        const float4 av = *reinterpret_cast<const float4*>(
            &As[(kc * 32 + kk) * 64 + ty * 4]);
        const float4 bv = *reinterpret_cast<const float4*>(
            &Bs[kk * 64 + tx * 4]);
        const float a[4] = {av.x, av.y, av.z, av.w};
        const float b[4] = {bv.x, bv.y, bv.z, bv.w};
#pragma unroll
        for (int i = 0; i < 4; ++i)
#pragma unroll
          for (int j = 0; j < 4; ++j) acc[i][j] = fmaf(a[i], b[j], acc[i][j]);
      }
    }
#pragma unroll
    for (int i = 0; i < 4; ++i)
#pragma unroll
      for (int j = 0; j < 4; ++j) {
        const float dv = __fsub_rn(srw[i], 2.0f * acc[i][j]);
        if (dv < bd[i]) { bd[i] = dv; bi[i] = n0 + tx * 4 + j; }
      }
  }
  __syncthreads();
  float2* merge = reinterpret_cast<float2*>(As);
#pragma unroll
  for (int i = 0; i < 4; ++i)
    merge[(ty * 4 + i) * 16 + tx] = make_float2(bd[i], __int_as_float(bi[i]));
  __syncthreads();
  if (tid < 64) {
    float best = 3.4e38f;
    int   besti = 0x7fffffff;
    for (int t = 0; t < 16; ++t) {
      const float2 mv = merge[tid * 16 + t];
      const int ii = __float_as_int(mv.y);
      if (mv.x < best || (mv.x == best && ii < besti)) { best = mv.x; besti = ii; }
    }
    cand[m0 + tid] = besti;
  }
}

__global__ __launch_bounds__(256) void vq_outs(
    const float* __restrict__ z, const float* __restrict__ cb,
    const int* __restrict__ cand, float* __restrict__ out,
    double* __restrict__ bloss) {
  __shared__ double wsum[4];
  const int tid  = threadIdx.x;
  const int lane = tid & 63;
  const int wv   = tid >> 6;
  const int m    = blockIdx.x * 4 + wv;
  const int b    = m >> 10;
  const int hw   = m & 1023;
  const float* zr = z + ((size_t)b << 18) + hw;
  const int best = cand[m];
  const float* e = cb + (size_t)best * kDim;
  float* o0 = out + ((size_t)b << 18) + hw;
  double acc = 0;
#pragma unroll
  for (int j = 0; j < 4; ++j) {
    const int d = lane + j * 64;
    const float ev = e[d];
    const float zv = zr[(size_t)d << 10];
    o0[(size_t)d << 10] = ev;
    const double diff = (double)ev - (double)zv;
    acc += diff * diff;
  }
#pragma unroll
  for (int off = 32; off > 0; off >>= 1) acc += __shfl_xor(acc, off);
  if (lane == 0) {
    out[kOutIdx + m] = (float)best;
    wsum[wv] = acc;
  }
  __syncthreads();
  if (tid == 0) bloss[blockIdx.x] = wsum[0] + wsum[1] + wsum[2] + wsum[3];
}

extern "C" void kernel_launch(void* const* d_in, const int* in_sizes, int n_in,
                              void* d_out, int out_size, void* d_ws, size_t ws_size,
                              hipStream_t stream) {
  const float* z  = (const float*)d_in[0];
  const float* cb = (const float*)d_in[1];
  float* out = (float*)d_out;

  if (ws_size >= kWsNeed) {
    unsigned short* zF  = (unsigned short*)((char*)d_ws + kOffZf);
    unsigned short* cbF = (unsigned short*)((char*)d_ws + kOffCbf);
    float4*   tt    = (float4*)((char*)d_ws + kOffTt);
    float*    zT    = (float*)((char*)d_ws + kOffZt);   // overlays zF/cbF/tt[0:4MB]
    float*    srow  = (float*)((char*)d_ws + kOffSrow);
    u64*      pack  = (u64*)((char*)d_ws + kOffPack);
    u64*      listS = (u64*)((char*)d_ws + kOffListS);
    u64*      listF = (u64*)((char*)d_ws + kOffListF);
    unsigned* cnts  = (unsigned*)((char*)d_ws + kOffCnt);
    double*   bloss = (double*)((char*)d_ws + kOffBloss);

    vq_convz <<<2048, 256, 0, stream>>>(z, zF);
    vq_convcb<<<1024, 256, 0, stream>>>(cb, cbF);
    vq_rows  <<<kRows / 256, 256, 0, stream>>>(z, srow, pack, cnts);
    vq_gemmT <<<8192, 256, 0, stream>>>(zF, cbF, tt);
    vq_mrg   <<<kRows / 256, 256, 0, stream>>>(tt, listS, listF, cnts);
    vq_trz   <<<dim3(kRows / 64, kDim / 64), 256, 0, stream>>>(z, zT);
    vq_resS  <<<256, 256, 0, stream>>>(zT, cb, srow, listS, cnts, pack);
    vq_resF  <<<256, 256, 0, stream>>>(zT, cb, srow, listF, cnts, pack);
    vq_out2  <<<kRows / 4, 256, 0, stream>>>(zT, cb, pack, out, bloss);
    vq_final <<<1, 256, 0, stream>>>(bloss, out);
  } else {
    int*    cand  = (int*)d_ws;
    double* bloss = (double*)((char*)d_ws + kRows * sizeof(int));
    vq_pass1s<<<kRows / 64, 256, 0, stream>>>(z, cb, cand);
    vq_outs  <<<kRows / 4,  256, 0, stream>>>(z, cb, cand, out, bloss);
    vq_final <<<1, 256, 0, stream>>>(bloss, out);
  }
}

// Round 9
// 327.372 us; speedup vs baseline: 3.8432x; 1.1027x over previous
//
#include <hip/hip_runtime.h>

typedef short  bhalf8  __attribute__((ext_vector_type(8)));
typedef float  floatx4 __attribute__((ext_vector_type(4)));
typedef unsigned long long u64;

namespace {
constexpr int kDim   = 256;
constexpr int kCodes = 8192;
constexpr int kRows  = 16384;   // 16 * 32 * 32
constexpr int kOutZq   = 16 * 256 * 32 * 32;  // 4194304
constexpr int kOutLoss = kOutZq;
constexpr int kOutIdx  = kOutZq + 1;
constexpr int kNT = 32;                        // 256-code tiles
constexpr unsigned kCapS = 131072, kCapF = 32768;
constexpr float kMargin = 4e-5f;  // half-bin 1.53e-5 + approx-err tail (validated R4-R8)

// ws layout (bytes). zT (16 MB f32 [m][k]) overlays zF+cbF+4MB slack, written
// AFTER the GEMM. tt sits ABOVE the zT window so mrg and trz can run fused.
constexpr size_t kOffZf    = 0;                                     // 8 MB
constexpr size_t kOffCbf   = kOffZf  + (size_t)kRows  * kDim * 2;   // 4 MB
constexpr size_t kOffZt    = 0;                                     // 16 MB overlay
constexpr size_t kOffTt    = 16u << 20;                             // 8 MB
constexpr size_t kOffSrow  = kOffTt   + (size_t)kNT * kRows * 16;
constexpr size_t kOffPack  = kOffSrow + (size_t)kRows * 4;
constexpr size_t kOffListS = kOffPack + (size_t)kRows * 8;
constexpr size_t kOffListF = kOffListS + (size_t)kCapS * 8;
constexpr size_t kOffCnt   = kOffListF + (size_t)kCapF * 8;
constexpr size_t kOffBloss = kOffCnt  + 256;
constexpr int    kNBloss   = kRows / 32;                            // 512
constexpr size_t kWsNeed   = kOffBloss + (size_t)kNBloss * 8;       // ~25.6 MB
}

__device__ inline unsigned short f2bf(float f) {  // RNE f32 -> bf16
  unsigned u = __float_as_uint(f);
  u += 0x7fffu + ((u >> 16) & 1u);
  return (unsigned short)(u >> 16);
}

__device__ inline void gload_lds16(const void* g, void* l) {
  __builtin_amdgcn_global_load_lds(
      (const __attribute__((address_space(1))) unsigned int*)(g),
      (__attribute__((address_space(3))) unsigned int*)(l), 16, 0, 0);
}

__device__ inline bool lexgt(float v, int iv, float w, int iw) {
  return v > w || (v == w && iv < iw);
}

// Fused prep: [0,2048) convz, [2048,3072) convcb, [3072,3136) rows+init.
__global__ __launch_bounds__(256) void vq_prep(
    const float* __restrict__ z, const float* __restrict__ cb,
    unsigned short* __restrict__ zF, unsigned short* __restrict__ cbF,
    float* __restrict__ srow, u64* __restrict__ pack,
    unsigned* __restrict__ cnts) {
  const int bid = blockIdx.x;
  if (bid < 2048) {
    // z [b][d][hw] f32 -> zF [kb=8][rt=1024][lane=64][8] bf16 fragment order.
    const int t    = bid * 256 + threadIdx.x;
    const int kb   = t >> 16;
    const int rt   = (t >> 6) & 1023;
    const int lane = t & 63;
    const int m  = rt * 16 + (lane & 15);
    const int k0 = kb * 32 + (lane >> 4) * 8;
    const int b  = m >> 10, hw = m & 1023;
    const float* zp = z + ((size_t)b << 18) + hw;
    bhalf8 v;
#pragma unroll
    for (int j = 0; j < 8; ++j)
      v[j] = (short)f2bf(zp[(size_t)(k0 + j) << 10]);
    *reinterpret_cast<bhalf8*>(&zF[(size_t)t << 3]) = v;
  } else if (bid < 3072) {
    // cb [n][d] f32 -> cbF [kb=8][ct=512][lane=64][8] bf16 fragment order.
    const int t    = (bid - 2048) * 256 + threadIdx.x;
    const int kb   = t >> 15;
    const int ct   = (t >> 6) & 511;
    const int lane = t & 63;
    const int col = ct * 16 + (lane & 15);
    const int k0  = kb * 32 + (lane >> 4) * 8;
    const float4 a = *reinterpret_cast<const float4*>(&cb[(size_t)col * kDim + k0]);
    const float4 c = *reinterpret_cast<const float4*>(&cb[(size_t)col * kDim + k0 + 4]);
    bhalf8 v;
    v[0] = (short)f2bf(a.x); v[1] = (short)f2bf(a.y);
    v[2] = (short)f2bf(a.z); v[3] = (short)f2bf(a.w);
    v[4] = (short)f2bf(c.x); v[5] = (short)f2bf(c.y);
    v[6] = (short)f2bf(c.z); v[7] = (short)f2bf(c.w);
    *reinterpret_cast<bhalf8*>(&cbF[(size_t)t << 3]) = v;
  } else {
    // Per-row s = sum(z^2), EXACT same f32 op order as the validated R2 kernel.
    const int m  = (bid - 3072) * 256 + threadIdx.x;
    const int b  = m >> 10, hw = m & 1023;
    const float* zp = z + ((size_t)b << 18) + hw;
    float r8[8];
#pragma unroll
    for (int j = 0; j < 8; ++j) {
      const float v = zp[(size_t)j << 10];
      r8[j] = __fmul_rn(v, v);
    }
    for (int d = 8; d < kDim; d += 8) {
#pragma unroll
      for (int j = 0; j < 8; ++j) {
        const float v = zp[(size_t)(d + j) << 10];
        r8[j] = __fadd_rn(r8[j], __fmul_rn(v, v));
      }
    }
    srow[m] = __fadd_rn(
        __fadd_rn(__fadd_rn(r8[0], r8[1]), __fadd_rn(r8[2], r8[3])),
        __fadd_rn(__fadd_rn(r8[4], r8[5]), __fadd_rn(r8[6], r8[7])));
    pack[m] = ~0ull;
    if (m == 0) { cnts[0] = 0u; cnts[1] = 0u; }
  }
}

// A-in-registers streaming bf16 MFMA GEMM.
// Block = 256 codes (A: 32 bhalf8/wave = full K in VGPRs) x 1024 zrows
// streamed as 16 m-tiles of 64 rows. Per m-tile: stage next B-tile (32 KB,
// full K) via global_load_lds (issued a whole compute-tile early -> the
// __syncthreads vmcnt-drain is free), 8 kb x 16 MFMA, top-2 epilogue.
// Scores bit-identical to R4-R8 (same operands, same kb-ascending chain).
__global__ __launch_bounds__(256, 2) void vq_gemmF(
    const unsigned short* __restrict__ zF,
    const unsigned short* __restrict__ cbF,
    float4* __restrict__ tt) {
  __shared__ __align__(16) unsigned short Bs[2][16384];  // 32 KB each
  __shared__ float4 wtop[4][64];
  const int tid  = threadIdx.x;
  const int nt   = blockIdx.x & 31;       // code-tile (256 codes)
  const int mc   = blockIdx.x >> 5;       // m-chunk (1024 zrows)
  const int w    = tid >> 6, lane = tid & 63;
  const int r16  = lane & 15, kg = lane >> 4;

  // A: wave w holds codes nt*256 + w*64 .. +64, all K: af[kb][mi].
  bhalf8 af[8][4];
#pragma unroll
  for (int kb = 0; kb < 8; ++kb)
#pragma unroll
    for (int mi = 0; mi < 4; ++mi)
      af[kb][mi] = *reinterpret_cast<const bhalf8*>(
          &cbF[((size_t)((kb * 512 + nt * 16 + w * 4 + mi) * 64 + lane)) << 3]);

  auto stage = [&](int mt, int buf) {  // 32 KB B-tile: 8 x gload_lds16/thread
    const int rtg0 = mc * 64 + mt * 4;
#pragma unroll
    for (int kb = 0; kb < 8; ++kb)
      gload_lds16(zF + (((size_t)(kb * 1024 + rtg0)) << 9) + (tid << 3),
                  &Bs[buf][kb * 2048 + tid * 8]);
  };

  auto merge2 = [&](float& a1, int& i1, float& a2, int& i2,
                    float b1, int j1, float b2, int j2) {
    if (lexgt(b1, j1, a1, i1)) {
      if (lexgt(b2, j2, a1, i1)) { a2 = b2; i2 = j2; }
      else                       { a2 = a1; i2 = i1; }
      a1 = b1; i1 = j1;
    } else if (lexgt(b1, j1, a2, i2)) {
      a2 = b1; i2 = j1;
    }
  };

  stage(0, 0);
  __syncthreads();

#pragma unroll 1
  for (int mt = 0; mt < 16; ++mt) {
    if (mt < 15) stage(mt + 1, (mt + 1) & 1);
    const unsigned short* bb = Bs[mt & 1];

    floatx4 acc[4][4];
#pragma unroll
    for (int i = 0; i < 4; ++i)
#pragma unroll
      for (int j = 0; j < 4; ++j) acc[i][j] = floatx4{0.f, 0.f, 0.f, 0.f};

#pragma unroll
    for (int kb = 0; kb < 8; ++kb) {
      bhalf8 bf[4];
#pragma unroll
      for (int ni = 0; ni < 4; ++ni)
        bf[ni] = *reinterpret_cast<const bhalf8*>(
            &bb[kb * 2048 + ni * 512 + lane * 8]);
#pragma unroll
      for (int mi = 0; mi < 4; ++mi)
#pragma unroll
        for (int ni = 0; ni < 4; ++ni)
          acc[mi][ni] = __builtin_amdgcn_mfma_f32_16x16x32_bf16(
              af[kb][mi], bf[ni], acc[mi][ni], 0, 0, 0);
    }

    // Epilogue: per zrow-group ni, top-2 over this wave's 64 codes.
    // C frag: code = w*64 + mi*16 + kg*4 + reg, zrow = ni*16 + r16.
#pragma unroll
    for (int ni = 0; ni < 4; ++ni) {
      float a1 = -3.4e38f, a2 = -3.4e38f;
      int   i1 = 0x7fffffff, i2 = 0x7fffffff;
#pragma unroll
      for (int mi = 0; mi < 4; ++mi)
#pragma unroll
        for (int reg = 0; reg < 4; ++reg) {
          const float v = acc[mi][ni][reg];
          const int  ix = nt * 256 + w * 64 + mi * 16 + kg * 4 + reg;
          if (lexgt(v, ix, a1, i1)) { a2 = a1; i2 = i1; a1 = v; i1 = ix; }
          else if (lexgt(v, ix, a2, i2)) { a2 = v; i2 = ix; }
        }
#pragma unroll
      for (int off = 16; off < 64; off <<= 1) {
        const float b1 = __shfl_xor(a1, off);
        const int   j1 = __shfl_xor(i1, off);
        const float b2 = __shfl_xor(a2, off);
        const int   j2 = __shfl_xor(i2, off);
        merge2(a1, i1, a2, i2, b1, j1, b2, j2);
      }
      if (kg == 0)
        wtop[w][ni * 16 + r16] = make_float4(a1, __int_as_float(i1),
                                             a2, __int_as_float(i2));
    }
    __syncthreads();
    if (tid < 64) {
      float4 e = wtop[0][tid];
      float a1 = e.x, a2 = e.z;
      int   i1 = __float_as_int(e.y), i2 = __float_as_int(e.w);
#pragma unroll
      for (int q = 1; q < 4; ++q) {
        e = wtop[q][tid];
        merge2(a1, i1, a2, i2, e.x, __float_as_int(e.y),
               e.z, __float_as_int(e.w));
      }
      tt[(size_t)nt * kRows + mc * 1024 + mt * 64 + tid] =
          make_float4(a1, __int_as_float(i1), a2, __int_as_float(i2));
    }
    __syncthreads();
  }
}

// Fused: [0,64) mrg (row-max + candidate emit), [64,1088) trz (z -> zT f32).
__global__ __launch_bounds__(256) void vq_mt(
    const float4* __restrict__ tt, u64* __restrict__ listS,
    u64* __restrict__ listF, unsigned* __restrict__ cnts,
    const float* __restrict__ z, float* __restrict__ zT) {
  __shared__ float t[64][65];
  const int bid = blockIdx.x;
  if (bid < 64) {
    const int m = bid * 256 + threadIdx.x;
    float M = -3.4e38f;
    for (int nt = 0; nt < kNT; ++nt)
      M = fmaxf(M, tt[(size_t)nt * kRows + m].x);
    const float thr = M - kMargin;
    for (int nt = 0; nt < kNT; ++nt) {
      const float4 e = tt[(size_t)nt * kRows + m];
      if (e.z > thr) {  // tile 2nd-best also in margin: full-tile exact scan
        const unsigned slot = atomicAdd(&cnts[1], 1u);
        if (slot < kCapF)
          listF[slot] = ((u64)(unsigned)m << 32) | (unsigned)nt;
      } else if (e.x > thr) {
        const unsigned slot = atomicAdd(&cnts[0], 1u);
        if (slot < kCapS)
          listS[slot] = ((u64)(unsigned)m << 32) | (unsigned)__float_as_int(e.y);
      }
    }
  } else {
    const int tr = bid - 64;        // 1024 tiles: 256 m-tiles x 4 d-tiles
    const int m0 = (tr >> 2) * 64;
    const int d0 = (tr & 3) * 64;
    const int b  = m0 >> 10;
    const int hw0 = m0 & 1023;
    const int tx = threadIdx.x & 15;
    const int r  = threadIdx.x >> 4;
    const float* zp = z + ((size_t)b << 18) + hw0;
    for (int rr = r; rr < 64; rr += 16) {
      const float4 v = *reinterpret_cast<const float4*>(
          &zp[((size_t)(d0 + rr) << 10) + tx * 4]);
      t[tx * 4 + 0][rr] = v.x; t[tx * 4 + 1][rr] = v.y;
      t[tx * 4 + 2][rr] = v.z; t[tx * 4 + 3][rr] = v.w;
    }
    __syncthreads();
    for (int rr = r; rr < 64; rr += 16) {
      float4 w;
      w.x = t[rr][tx * 4 + 0]; w.y = t[rr][tx * 4 + 1];
      w.z = t[rr][tx * 4 + 2]; w.w = t[rr][tx * 4 + 3];
      *reinterpret_cast<float4*>(&zT[(size_t)(m0 + rr) * kDim + d0 + tx * 4]) = w;
    }
  }
}

// Exact f32 rescore (bit-identical chain: ascending-k fmaf; zT values == z).
__device__ inline void rescore_oneT(const float* __restrict__ zT,
                                    const float* __restrict__ cb,
                                    const float* __restrict__ srow,
                                    u64* __restrict__ pack, int m, int code) {
  const float* zr = zT + (size_t)m * kDim;
  const float* er = cb + (size_t)code * kDim;
  float d = 0.f;
  for (int k = 0; k < kDim; ++k) d = fmaf(zr[k], er[k], d);
  const float dv = __fsub_rn(srow[m], 2.0f * d);
  atomicMin(pack + m, ((u64)__float_as_uint(dv) << 32) | (unsigned)code);
}

// Fused rescore: blocks [0,128) singles per-thread; [128,256) flagged tiles
// wave-parallel (4 codes/lane, ILP-fused chains). Same numerics.
__global__ __launch_bounds__(256) void vq_resc(
    const float* __restrict__ zT, const float* __restrict__ cb,
    const float* __restrict__ srow, const u64* __restrict__ listS,
    const u64* __restrict__ listF, const unsigned* __restrict__ cnts,
    u64* __restrict__ pack) {
  const int bid = blockIdx.x;
  if (bid < 128) {
    const unsigned total = min(cnts[0], kCapS);
    for (unsigned i = bid * 256 + threadIdx.x; i < total; i += 128 * 256) {
      const u64 e = listS[i];
      rescore_oneT(zT, cb, srow, pack, (int)(e >> 32), (int)(e & 0xffffffffu));
    }
  } else {
    const unsigned total = min(cnts[1], kCapF);
    const int lane = threadIdx.x & 63;
    const unsigned wid = ((bid - 128) * 256 + threadIdx.x) >> 6;
    for (unsigned i = wid; i < total; i += 128 * 4) {
      const u64 e = listF[i];
      const int m  = (int)(e >> 32);
      const int c0 = (int)(e & 0xffffffffu) * 256 + lane;
      const float* zr = zT + (size_t)m * kDim;
      const float* e0 = cb + (size_t)(c0 +   0) * kDim;
      const float* e1 = cb + (size_t)(c0 +  64) * kDim;
      const float* e2 = cb + (size_t)(c0 + 128) * kDim;
      const float* e3 = cb + (size_t)(c0 + 192) * kDim;
      float d0 = 0.f, d1 = 0.f, d2 = 0.f, d3 = 0.f;
      for (int k = 0; k < kDim; ++k) {
        const float zv = zr[k];
        d0 = fmaf(zv, e0[k], d0); d1 = fmaf(zv, e1[k], d1);
        d2 = fmaf(zv, e2[k], d2); d3 = fmaf(zv, e3[k], d3);
      }
      const float s = srow[m];
      atomicMin(pack + m, ((u64)__float_as_uint(__fsub_rn(s, 2.0f * d0)) << 32) | (unsigned)(c0));
      atomicMin(pack + m, ((u64)__float_as_uint(__fsub_rn(s, 2.0f * d1)) << 32) | (unsigned)(c0 + 64));
      atomicMin(pack + m, ((u64)__float_as_uint(__fsub_rn(s, 2.0f * d2)) << 32) | (unsigned)(c0 + 128));
      atomicMin(pack + m, ((u64)__float_as_uint(__fsub_rn(s, 2.0f * d3)) << 32) | (unsigned)(c0 + 192));
    }
  }
}

// Output: LDS-transposed z_q writes (contiguous 256B d-segments, no 16x
// write amplification), idx, f64 loss partials. Block = 32 rows.
__global__ __launch_bounds__(256) void vq_outT(
    const float* __restrict__ zT, const float* __restrict__ cb,
    const u64* __restrict__ pack, float* __restrict__ out,
    double* __restrict__ bloss) {
  __shared__ __align__(16) float zq[32][260];
  __shared__ int bests[32];
  __shared__ double wsum[4];
  const int tid  = threadIdx.x;
  const int lane = tid & 63;
  const int w    = tid >> 6;
  const int m0   = blockIdx.x * 32;
  if (tid < 32) {
    const u64 p = pack[m0 + tid];
    const int best = (p == ~0ull) ? 0 : (int)(p & 0x7fffffffu);
    bests[tid] = best;
    out[kOutIdx + m0 + tid] = (float)best;
  }
  __syncthreads();
  double acc = 0;
#pragma unroll
  for (int rr = 0; rr < 8; ++rr) {   // wave w: rows w*8..+8
    const int r = w * 8 + rr;
    const float4 e = *reinterpret_cast<const float4*>(
        &cb[(size_t)bests[r] * kDim + lane * 4]);
    *reinterpret_cast<float4*>(&zq[r][lane * 4]) = e;
    const float4 zv = *reinterpret_cast<const float4*>(
        &zT[(size_t)(m0 + r) * kDim + lane * 4]);
    const double dx = (double)e.x - (double)zv.x;
    const double dy = (double)e.y - (double)zv.y;
    const double dz = (double)e.z - (double)zv.z;
    const double dw = (double)e.w - (double)zv.w;
    acc += dx * dx + dy * dy + dz * dz + dw * dw;
  }
#pragma unroll
  for (int off = 32; off > 0; off >>= 1) acc += __shfl_xor(acc, off);
  if (lane == 0) wsum[w] = acc;
  __syncthreads();
  // Write phase: thread = d; 32 hw values per d, contiguous float4 stores.
  const int b   = m0 >> 10;
  const int hw0 = m0 & 1023;
  float* o = out + ((size_t)b << 18) + ((size_t)tid << 10) + hw0;
#pragma unroll
  for (int j = 0; j < 8; ++j) {
    float4 v;
    v.x = zq[j * 4 + 0][tid];
    v.y = zq[j * 4 + 1][tid];
    v.z = zq[j * 4 + 2][tid];
    v.w = zq[j * 4 + 3][tid];
    *reinterpret_cast<float4*>(&o[j * 4]) = v;
  }
  if (tid == 0)
    bloss[blockIdx.x] = wsum[0] + wsum[1] + wsum[2] + wsum[3];
}

__global__ __launch_bounds__(256) void vq_final(
    const double* __restrict__ bloss, float* __restrict__ out, int n) {
  __shared__ double sm[256];
  double s = 0;
  for (int i = threadIdx.x; i < n; i += 256) s += bloss[i];
  sm[threadIdx.x] = s;
  __syncthreads();
  for (int st = 128; st > 0; st >>= 1) {
    if (threadIdx.x < st) sm[threadIdx.x] += sm[threadIdx.x + st];
    __syncthreads();
  }
  if (threadIdx.x == 0)
    out[kOutLoss] = (float)(1.25 * sm[0] / (double)kOutZq);
}

// ---------------- fallback path (verbatim Round-2, proven; 96 KB ws) ------

__global__ __launch_bounds__(256) void vq_pass1s(
    const float* __restrict__ z, const float* __restrict__ cb,
    int* __restrict__ cand) {
  __shared__ __align__(16) float As[kDim * 64];
  __shared__ __align__(16) float Bs[32 * 64];
  __shared__ float Ss[64];
  const int tid = threadIdx.x;
  const int m0  = blockIdx.x * 64;
  {
    const int r  = tid & 63;
    const int d0 = tid >> 6;
    const int n  = m0 + r;
    const int b  = n >> 10;
    const int hw = n & 1023;
    const float* zp = z + ((size_t)b << 18) + hw;
    for (int j = 0; j < 64; ++j) {
      const int d = d0 + (j << 2);
      As[d * 64 + r] = zp[(size_t)d << 10];
    }
  }
  __syncthreads();
  if (tid < 64) {
    float r8[8];
#pragma unroll
    for (int j = 0; j < 8; ++j) {
      const float v = As[j * 64 + tid];
      r8[j] = __fmul_rn(v, v);
    }
    for (int d = 8; d < kDim; d += 8) {
#pragma unroll
      for (int j = 0; j < 8; ++j) {
        const float v = As[(d + j) * 64 + tid];
        r8[j] = __fadd_rn(r8[j], __fmul_rn(v, v));
      }
    }
    Ss[tid] = __fadd_rn(
        __fadd_rn(__fadd_rn(r8[0], r8[1]), __fadd_rn(r8[2], r8[3])),
        __fadd_rn(__fadd_rn(r8[4], r8[5]), __fadd_rn(r8[6], r8[7])));
  }
  __syncthreads();
  const int tx = tid & 15;
  const int ty = tid >> 4;
  float srw[4];
#pragma unroll
  for (int i = 0; i < 4; ++i) srw[i] = Ss[ty * 4 + i];
  float bd[4]; int bi[4];
#pragma unroll
  for (int i = 0; i < 4; ++i) { bd[i] = 3.4e38f; bi[i] = 0; }
  for (int n0 = 0; n0 < kCodes; n0 += 64) {
    float acc[4][4];
#pragma unroll
    for (int i = 0; i < 4; ++i)
#pragma unroll
      for (int j = 0; j < 4; ++j) acc[i][j] = 0.f;
    for (int kc = 0; kc < kDim / 32; ++kc) {
      __syncthreads();
#pragma unroll
      for (int rep = 0; rep < 2; ++rep) {
        const int s  = tid + rep * 256;
        const int c  = s >> 3;
        const int fo = (s & 7) << 2;
        const float4 v = *reinterpret_cast<const float4*>(
            &cb[(size_t)(n0 + c) * kDim + kc * 32 + fo]);
        Bs[(fo + 0) * 64 + c] = v.x;
        Bs[(fo + 1) * 64 + c] = v.y;
        Bs[(fo + 2) * 64 + c] = v.z;
        Bs[(fo + 3) * 64 + c] = v.w;
      }
      __syncthreads();
#pragma unroll
      for (int kk = 0; kk < 32; ++kk) {
        const float4 av = *reinterpret_cast<const float4*>(
            &As[(kc * 32 + kk) * 64 + ty * 4]);
        const float4 bv = *reinterpret_cast<const float4*>(
            &Bs[kk * 64 + tx * 4]);
        const float a[4] = {av.x, av.y, av.z, av.w};
        const float b[4] = {bv.x, bv.y, bv.z, bv.w};
#pragma unroll
        for (int i = 0; i < 4; ++i)
#pragma unroll
          for (int j = 0; j < 4; ++j) acc[i][j] = fmaf(a[i], b[j], acc[i][j]);
      }
    }
#pragma unroll
    for (int i = 0; i < 4; ++i)
#pragma unroll
      for (int j = 0; j < 4; ++j) {
        const float dv = __fsub_rn(srw[i], 2.0f * acc[i][j]);
        if (dv < bd[i]) { bd[i] = dv; bi[i] = n0 + tx * 4 + j; }
      }
  }
  __syncthreads();
  float2* merge = reinterpret_cast<float2*>(As);
#pragma unroll
  for (int i = 0; i < 4; ++i)
    merge[(ty * 4 + i) * 16 + tx] = make_float2(bd[i], __int_as_float(bi[i]));
  __syncthreads();
  if (tid < 64) {
    float best = 3.4e38f;
    int   besti = 0x7fffffff;
    for (int t = 0; t < 16; ++t) {
      const float2 mv = merge[tid * 16 + t];
      const int ii = __float_as_int(mv.y);
      if (mv.x < best || (mv.x == best && ii < besti)) { best = mv.x; besti = ii; }
    }
    cand[m0 + tid] = besti;
  }
}

__global__ __launch_bounds__(256) void vq_outs(
    const float* __restrict__ z, const float* __restrict__ cb,
    const int* __restrict__ cand, float* __restrict__ out,
    double* __restrict__ bloss) {
  __shared__ double wsum[4];
  const int tid  = threadIdx.x;
  const int lane = tid & 63;
  const int wv   = tid >> 6;
  const int m    = blockIdx.x * 4 + wv;
  const int b    = m >> 10;
  const int hw   = m & 1023;
  const float* zr = z + ((size_t)b << 18) + hw;
  const int best = cand[m];
  const float* e = cb + (size_t)best * kDim;
  float* o0 = out + ((size_t)b << 18) + hw;
  double acc = 0;
#pragma unroll
  for (int j = 0; j < 4; ++j) {
    const int d = lane + j * 64;
    const float ev = e[d];
    const float zv = zr[(size_t)d << 10];
    o0[(size_t)d << 10] = ev;
    const double diff = (double)ev - (double)zv;
    acc += diff * diff;
  }
#pragma unroll
  for (int off = 32; off > 0; off >>= 1) acc += __shfl_xor(acc, off);
  if (lane == 0) {
    out[kOutIdx + m] = (float)best;
    wsum[wv] = acc;
  }
  __syncthreads();
  if (tid == 0) bloss[blockIdx.x] = wsum[0] + wsum[1] + wsum[2] + wsum[3];
}

extern "C" void kernel_launch(void* const* d_in, const int* in_sizes, int n_in,
                              void* d_out, int out_size, void* d_ws, size_t ws_size,
                              hipStream_t stream) {
  const float* z  = (const float*)d_in[0];
  const float* cb = (const float*)d_in[1];
  float* out = (float*)d_out;

  if (ws_size >= kWsNeed) {
    unsigned short* zF  = (unsigned short*)((char*)d_ws + kOffZf);
    unsigned short* cbF = (unsigned short*)((char*)d_ws + kOffCbf);
    float*    zT    = (float*)((char*)d_ws + kOffZt);   // overlays zF/cbF
    float4*   tt    = (float4*)((char*)d_ws + kOffTt);
    float*    srow  = (float*)((char*)d_ws + kOffSrow);
    u64*      pack  = (u64*)((char*)d_ws + kOffPack);
    u64*      listS = (u64*)((char*)d_ws + kOffListS);
    u64*      listF = (u64*)((char*)d_ws + kOffListF);
    unsigned* cnts  = (unsigned*)((char*)d_ws + kOffCnt);
    double*   bloss = (double*)((char*)d_ws + kOffBloss);

    vq_prep <<<3136, 256, 0, stream>>>(z, cb, zF, cbF, srow, pack, cnts);
    vq_gemmF<<<512,  256, 0, stream>>>(zF, cbF, tt);
    vq_mt   <<<1088, 256, 0, stream>>>(tt, listS, listF, cnts, z, zT);
    vq_resc <<<256,  256, 0, stream>>>(zT, cb, srow, listS, listF, cnts, pack);
    vq_outT <<<kRows / 32, 256, 0, stream>>>(zT, cb, pack, out, bloss);
    vq_final<<<1, 256, 0, stream>>>(bloss, out, kNBloss);
  } else {
    int*    cand  = (int*)d_ws;
    double* bloss = (double*)((char*)d_ws + kRows * sizeof(int));
    vq_pass1s<<<kRows / 64, 256, 0, stream>>>(z, cb, cand);
    vq_outs  <<<kRows / 4,  256, 0, stream>>>(z, cb, cand, out, bloss);
    vq_final <<<1, 256, 0, stream>>>(bloss, out, kRows / 4);
  }
}